// Round 10
// baseline (900.619 us; speedup 1.0000x reference)
//
#include <hip/hip_runtime.h>

#define NW 512
#define WT 128
#define DM 768
#define NH 12

typedef __attribute__((ext_vector_type(8))) short bf16x8;
typedef __attribute__((ext_vector_type(4))) float f32x4;
typedef __attribute__((ext_vector_type(4))) unsigned int u32x4;

#define W1CH 12288                            // one (head,chunk) attn W image (single bf16)
#define WS_W1 ((size_t)NH * 24 * W1CH)        // 3,538,944 attn W images
#define PWCHUNK 49152                         // one proj W k32 chunk image
#define WS_W2 ((size_t)24 * PWCHUNK)          // 1,179,648 proj W image
#define IMG_SZ 81920                          // per-(window,head) q/k/v image

__device__ __forceinline__ unsigned short bf_rne(float v) {
  unsigned u = __float_as_uint(v);
  unsigned r = u + 0x7fffu + ((u >> 16) & 1u);
  return (unsigned short)(r >> 16);
}
__device__ __forceinline__ void bf_split(float v, unsigned short& hi, unsigned short& lo) {
  hi = bf_rne(v);
  float hf = __uint_as_float(((unsigned)hi) << 16);
  lo = bf_rne(v - hf);
}

__device__ __forceinline__ unsigned cvt_pk_bf16(float a, float b) {
  unsigned r;
  asm("v_cvt_pk_bf16_f32 %0, %1, %2" : "=v"(r) : "v"(a), "v"(b));
  return r;
}
__device__ __forceinline__ unsigned short bf_rne_fast(float v) {
  return (unsigned short)cvt_pk_bf16(v, v);
}
__device__ __forceinline__ void bf_split_fast(float v, unsigned short& hi, unsigned short& lo) {
  unsigned hp = cvt_pk_bf16(v, v);
  float hf = __uint_as_float(hp << 16);
  lo = (unsigned short)cvt_pk_bf16(v - hf, v - hf);
  hi = (unsigned short)hp;
}

__device__ __forceinline__ void split8(float4 v0, float4 v1, bf16x8& hi, bf16x8& lo) {
  float f[8] = {v0.x, v0.y, v0.z, v0.w, v1.x, v1.y, v1.z, v1.w};
  u32x4 hu, lu;
#pragma unroll
  for (int i = 0; i < 4; ++i) {
    float e0 = f[2 * i], e1 = f[2 * i + 1];
    unsigned hp = cvt_pk_bf16(e0, e1);
    float h0 = __uint_as_float(hp << 16);
    float h1 = __uint_as_float(hp & 0xffff0000u);
    lu[i] = cvt_pk_bf16(e0 - h0, e1 - h1);
    hu[i] = hp;
  }
  hi = __builtin_bit_cast(bf16x8, hu);
  lo = __builtin_bit_cast(bf16x8, lu);
}

__device__ __forceinline__ void gl_lds16(const void* g, void* l) {
  __builtin_amdgcn_global_load_lds(
      (const __attribute__((address_space(1))) void*)g,
      (__attribute__((address_space(3))) void*)l, 16, 0, 0);
}
__device__ __forceinline__ void gl_lds4(const void* g, void* l) {
  __builtin_amdgcn_global_load_lds(
      (const __attribute__((address_space(1))) void*)g,
      (__attribute__((address_space(3))) void*)l, 4, 0, 0);
}

// ---------------- precompute: attn W -> single-bf16 swizzled LDS images ----
__global__ __launch_bounds__(256) void split_w_kernel(
    const float* __restrict__ qkv_w, unsigned char* __restrict__ wsW)
{
  int id = blockIdx.x * 256 + threadIdx.x;
  int c4 = id & 7;
  int j  = (id >> 3) % 192;
  int hc = (id >> 3) / 192;
  int c  = hc % 24;
  int h  = hc / 24;
  int sec = j >> 6, d = j & 63;
  const float* src = qkv_w + (size_t)(sec * DM + h * 64 + d) * DM + c * 32 + c4 * 4;
  float4 v = *(const float4*)src;
  uint2 hv;
  hv.x = (unsigned)bf_rne(v.x) | ((unsigned)bf_rne(v.y) << 16);
  hv.y = (unsigned)bf_rne(v.z) | ((unsigned)bf_rne(v.w) << 16);
  int byte = j * 64 + (((c4 >> 1) ^ ((j >> 1) & 3)) << 4) + ((c4 & 1) << 3);
  *(uint2*)(wsW + (size_t)hc * W1CH + byte) = hv;
}

// ---------------- precompute: proj W -> bf16 swizzled LDS image ------------
__global__ __launch_bounds__(256) void split_pw_kernel(
    const float* __restrict__ pw, unsigned char* __restrict__ wsP)
{
  int id = blockIdx.x * 256 + threadIdx.x;
  int c4 = id & 7;
  int n  = (id >> 3) % 768;
  int c  = (id >> 3) / 768;
  float4 v = *(const float4*)(pw + (size_t)n * DM + c * 32 + c4 * 4);
  uint2 hv;
  hv.x = (unsigned)bf_rne(v.x) | ((unsigned)bf_rne(v.y) << 16);
  hv.y = (unsigned)bf_rne(v.z) | ((unsigned)bf_rne(v.w) << 16);
  int byte = n * 64 + (((c4 >> 1) ^ ((n >> 1) & 3)) << 4) + ((c4 & 1) << 3);
  *(uint2*)(wsP + (size_t)c * PWCHUNK + byte) = hv;
}

// ---- shared image offsets (smem layout AND per-(window,head) ws image) ----
#define QH_OFF 0
#define QL_OFF 16384
#define KH_OFF 32768
#define KL_OFF 49152
#define VT_OFF 65536
#define EX_OFF 49152
#define P_OFF  0

// ================= SPLIT PATH K1: qkv GEMM, 2 windows/block ================
// M=256 (2 windows), N=192, 2-pass q/k, 1-pass v. Wave w: window w>>2,
// rows (w&3)*32 .. +32, ALL 12 n-strips -> 40 MFMA/wave/chunk.
// x direct-to-reg, depth-2 UNCONDITIONAL clamped prefetch; W dbuf 2x12KB.
// Epilogue writes swizzled q(hi/lo)/k(hi/lo)/vT images to ws.
__global__ __launch_bounds__(512, 2) void qkv2_kernel(
    const float* __restrict__ x, const unsigned char* __restrict__ wimg,
    const float* __restrict__ qkv_b, unsigned char* __restrict__ att, int p0)
{
  __shared__ __align__(16) unsigned char smem[24576];
  const int t = threadIdx.x;
  const int lane = t & 63;
  const int w = t >> 6;
  const int g = lane >> 4;
  const int ln = lane & 15;
  const int wm = w & 3;
  const int win = w >> 2;

  const int nwg = gridDim.x;
  const int orig = blockIdx.x;
  const int wg = (orig & 7) * (nwg >> 3) + (orig >> 3);
  const int h = wg % 12;
  const int lp = wg / 12;
  const int bn = 2 * (p0 + lp) + win;

  const float* xw = x + (size_t)bn * (WT * DM);
  const unsigned char* whead = wimg + (size_t)h * (24 * W1CH);
  unsigned char* img = att + ((size_t)(lp * 2 + win) * NH + h) * IMG_SZ;

  f32x4 acc[2][12];
#pragma unroll
  for (int i = 0; i < 2; ++i)
#pragma unroll
    for (int j = 0; j < 12; ++j) acc[i][j] = (f32x4){0.f, 0.f, 0.f, 0.f};

  const float* xp0 = xw + (size_t)(wm * 32 + ln) * DM + g * 8;
  const float* xp1 = xp0 + (size_t)16 * DM;

  // wave-uniform W staging: 1536 B/wave = 1 gl_lds16 + 2 gl_lds4 per thread
  auto stageW = [&](int c, int buf) {
    const unsigned char* s = whead + (size_t)c * W1CH + w * 1536;
    unsigned char* d = smem + buf * W1CH + w * 1536;
    gl_lds16(s + lane * 16, d + lane * 16);
    gl_lds4(s + 1024 + lane * 4, d + 1024 + lane * 4);
    gl_lds4(s + 1280 + lane * 4, d + 1280 + lane * 4);
  };

  // prologue: W(0)->buf0 ; x(0), x(1) to regs
  stageW(0, 0);
  __builtin_amdgcn_sched_barrier(0);
  float4 xc0 = *(const float4*)xp0;
  float4 xc1 = *(const float4*)(xp0 + 4);
  float4 xc2 = *(const float4*)xp1;
  float4 xc3 = *(const float4*)(xp1 + 4);
  float4 xn0 = *(const float4*)(xp0 + 32);
  float4 xn1 = *(const float4*)(xp0 + 36);
  float4 xn2 = *(const float4*)(xp1 + 32);
  float4 xn3 = *(const float4*)(xp1 + 36);
  __builtin_amdgcn_sched_barrier(0);

  for (int c = 0; c < 24; ++c) {
    // (a) issue x(c+2) UNCONDITIONALLY (clamped at tail -> vmcnt stays exact)
    int cn = (c + 2 < 24 ? c + 2 : 23) * 32;
    float4 nf0 = *(const float4*)(xp0 + cn);
    float4 nf1 = *(const float4*)(xp0 + cn + 4);
    float4 nf2 = *(const float4*)(xp1 + cn);
    float4 nf3 = *(const float4*)(xp1 + cn + 4);
    __builtin_amdgcn_sched_barrier(0);
    // (b) split x(c) (loaded 2 iters ago - already retired)
    bf16x8 ah0, al0, ah1, al1;
    split8(xc0, xc1, ah0, al0);
    split8(xc2, xc3, ah1, al1);
    __builtin_amdgcn_sched_barrier(0);
    // (c) retire through W(c), keep x(c+2) in flight; barrier
    asm volatile("s_waitcnt vmcnt(4)" ::: "memory");
    __builtin_amdgcn_s_barrier();
    __builtin_amdgcn_sched_barrier(0);
    // (d) stage W(c+1) (clamped-redundant at tail; targets idle buffer)
    {
      int cw = (c + 1 < 24 ? c + 1 : 23);
      stageW(cw, (c + 1) & 1);
    }
    __builtin_amdgcn_sched_barrier(0);
    // (e) MFMA on W(c): 12 strips, 2-pass for q/k (ns<8), 1-pass v
    const unsigned char* WH = smem + (c & 1) * W1CH;
    __builtin_amdgcn_s_setprio(1);
#pragma unroll
    for (int ns = 0; ns < 12; ++ns) {
      int j = ns * 16 + ln;
      int sw = j * 64 + ((g ^ ((j >> 1) & 3)) << 4);
      bf16x8 bh = *(const bf16x8*)(WH + sw);
      acc[0][ns] = __builtin_amdgcn_mfma_f32_16x16x32_bf16(ah0, bh, acc[0][ns], 0, 0, 0);
      acc[1][ns] = __builtin_amdgcn_mfma_f32_16x16x32_bf16(ah1, bh, acc[1][ns], 0, 0, 0);
      if (ns < 8) {
        acc[0][ns] = __builtin_amdgcn_mfma_f32_16x16x32_bf16(al0, bh, acc[0][ns], 0, 0, 0);
        acc[1][ns] = __builtin_amdgcn_mfma_f32_16x16x32_bf16(al1, bh, acc[1][ns], 0, 0, 0);
      }
    }
    __builtin_amdgcn_s_setprio(0);
    xc0 = xn0; xc1 = xn1; xc2 = xn2; xc3 = xn3;
    xn0 = nf0; xn1 = nf1; xn2 = nf2; xn3 = nf3;
  }

  // epilogue: bias + scatter to ws image (same byte formulas as smem layout)
#pragma unroll
  for (int ns = 0; ns < 12; ++ns) {
    int cc = ns * 16 + ln;
    int sec = cc >> 6, dd = cc & 63;
    float bias = qkv_b[sec * DM + h * 64 + dd];
#pragma unroll
    for (int sm = 0; sm < 2; ++sm) {
#pragma unroll
      for (int r = 0; r < 4; ++r) {
        int m = wm * 32 + sm * 16 + 4 * g + r;
        float val = acc[sm][ns][r] + bias;
        if (cc < 64) {
          val *= 0.125f;
          unsigned short hi, lo; bf_split_fast(val, hi, lo);
          int byte = m * 128 + (((dd >> 3) ^ (m & 7)) << 4) + ((dd & 7) << 1);
          *(unsigned short*)(img + QH_OFF + byte) = hi;
          *(unsigned short*)(img + QL_OFF + byte) = lo;
        } else if (cc < 128) {
          unsigned short hi, lo; bf_split_fast(val, hi, lo);
          int byte = m * 128 + (((dd >> 3) ^ (m & 7)) << 4) + ((dd & 7) << 1);
          *(unsigned short*)(img + KH_OFF + byte) = hi;
          *(unsigned short*)(img + KL_OFF + byte) = lo;
        } else {
          int byte = dd * 256 + ((((m >> 3) ^ (dd & 15))) << 4) + ((m & 7) << 1);
          *(unsigned short*)(img + VT_OFF + byte) = bf_rne_fast(val);
        }
      }
    }
  }
}

// ================= SPLIT PATH K2: attention from staged images =============
__global__ __launch_bounds__(512, 4) void attn2_kernel(
    const unsigned char* __restrict__ att, const float* __restrict__ edge_bias,
    const float* __restrict__ mask, float* __restrict__ out, int w0)
{
  __shared__ __align__(16) unsigned char smem[81920];
  const int t = threadIdx.x;
  const int lane = t & 63;
  const int w = t >> 6;
  const int g = lane >> 4;
  const int ln = lane & 15;

  const int nwg = gridDim.x;
  const int orig = blockIdx.x;
  const int wg = (orig & 7) * (nwg >> 3) + (orig >> 3);
  const int h = wg % 12;
  const int lw = wg / 12;
  const int bn = w0 + lw;

  // stage the 80 KB image 1:1 into smem (same offsets as writer)
  const unsigned char* img = att + ((size_t)lw * NH + h) * IMG_SZ;
#pragma unroll
  for (int i = 0; i < 10; ++i)
    gl_lds16(img + i * 8192 + t * 16, smem + i * 8192 + t * 16);
  asm volatile("s_waitcnt vmcnt(0)" ::: "memory");
  __syncthreads();

  // ---- Phase B: S = q @ k^T (split 3-pass), wave w owns rows w*16..+16
  const int mB = w * 16;
  f32x4 s2[8];
#pragma unroll
  for (int ns = 0; ns < 8; ++ns) s2[ns] = (f32x4){0.f, 0.f, 0.f, 0.f};
#pragma unroll
  for (int ks = 0; ks < 2; ++ks) {
    int arow = mB + ln;
    int abyte = arow * 128 + (((ks * 4 + g) ^ (arow & 7)) << 4);
    bf16x8 qh = *(const bf16x8*)(smem + QH_OFF + abyte);
    bf16x8 ql = *(const bf16x8*)(smem + QL_OFF + abyte);
#pragma unroll
    for (int ns = 0; ns < 8; ++ns) {
      int brow = ns * 16 + ln;
      int bbyte = brow * 128 + (((ks * 4 + g) ^ (brow & 7)) << 4);
      bf16x8 kh = *(const bf16x8*)(smem + KH_OFF + bbyte);
      bf16x8 kl = *(const bf16x8*)(smem + KL_OFF + bbyte);
      s2[ns] = __builtin_amdgcn_mfma_f32_16x16x32_bf16(qh, kh, s2[ns], 0, 0, 0);
      s2[ns] = __builtin_amdgcn_mfma_f32_16x16x32_bf16(qh, kl, s2[ns], 0, 0, 0);
      s2[ns] = __builtin_amdgcn_mfma_f32_16x16x32_bf16(ql, kh, s2[ns], 0, 0, 0);
    }
  }
  __syncthreads();   // q/k dead; P may overlay

  // ---- Phase C: softmax -> prune -> mask/eb -> softmax -> P (bf16)
  const float* mk = mask + (size_t)(bn & 127) * (WT * WT);
  const float* eb = edge_bias + (size_t)h * (WT * WT);
#pragma unroll
  for (int r = 0; r < 4; ++r) {
    int m = mB + 4 * g + r;
    float sv[8];
#pragma unroll
    for (int ns = 0; ns < 8; ++ns) sv[ns] = s2[ns][r];
    float m1 = sv[0];
#pragma unroll
    for (int ns = 1; ns < 8; ++ns) m1 = fmaxf(m1, sv[ns]);
#pragma unroll
    for (int off = 1; off < 16; off <<= 1) m1 = fmaxf(m1, __shfl_xor(m1, off, 64));
    float e[8], sum1 = 0.f;
#pragma unroll
    for (int ns = 0; ns < 8; ++ns) { e[ns] = __expf(sv[ns] - m1); sum1 += e[ns]; }
#pragma unroll
    for (int off = 1; off < 16; off <<= 1) sum1 += __shfl_xor(sum1, off, 64);
    float thr = 0.5f * sum1;
    float tv[8];
#pragma unroll
    for (int ns = 0; ns < 8; ++ns) {
      int col = ns * 16 + ln;
      float mkv = mk[m * WT + col];
      float ebv = eb[m * WT + col];
      float keep = (e[ns] > thr) ? 0.f : 1.f;
      float val = sv[ns] * keep * mkv * ebv;
      tv[ns] = (val == 0.f) ? -10000.f : val;
    }
    float m2 = tv[0];
#pragma unroll
    for (int ns = 1; ns < 8; ++ns) m2 = fmaxf(m2, tv[ns]);
#pragma unroll
    for (int off = 1; off < 16; off <<= 1) m2 = fmaxf(m2, __shfl_xor(m2, off, 64));
    float e2[8], sum2 = 0.f;
#pragma unroll
    for (int ns = 0; ns < 8; ++ns) { e2[ns] = __expf(tv[ns] - m2); sum2 += e2[ns]; }
#pragma unroll
    for (int off = 1; off < 16; off <<= 1) sum2 += __shfl_xor(sum2, off, 64);
    float inv = 1.f / sum2;
#pragma unroll
    for (int ns = 0; ns < 8; ++ns)
      *(unsigned short*)(smem + P_OFF + m * 272 + (ns * 16 + ln) * 2) = bf_rne_fast(e2[ns] * inv);
  }
  __syncthreads();

  // ---- Phase D: out = P @ v  (plain bf16)
  f32x4 o4[4];
#pragma unroll
  for (int ns = 0; ns < 4; ++ns) o4[ns] = (f32x4){0.f, 0.f, 0.f, 0.f};
#pragma unroll
  for (int ks = 0; ks < 4; ++ks) {
    bf16x8 pa = *(const bf16x8*)(smem + P_OFF + (mB + ln) * 272 + ks * 64 + g * 16);
#pragma unroll
    for (int ns = 0; ns < 4; ++ns) {
      int d = ns * 16 + ln;
      bf16x8 vb = *(const bf16x8*)(smem + VT_OFF + d * 256 + (((ks * 4 + g) ^ (d & 15)) << 4));
      o4[ns] = __builtin_amdgcn_mfma_f32_16x16x32_bf16(pa, vb, o4[ns], 0, 0, 0);
    }
  }
#pragma unroll
  for (int ns = 0; ns < 4; ++ns)
#pragma unroll
    for (int r = 0; r < 4; ++r)
      out[(size_t)bn * (WT * DM) + (size_t)(mB + 4 * g + r) * DM + h * 64 + ns * 16 + ln] = o4[ns][r];
}

// ======= fused fallback (round-9 verified, 660us): ws in [4.7MB, 67.6MB) ====
__global__ __launch_bounds__(512, 4) void attn_kernel_pre(
    const float* __restrict__ x, const unsigned char* __restrict__ wimg,
    const float* __restrict__ qkv_b, const float* __restrict__ edge_bias,
    const float* __restrict__ mask, float* __restrict__ out)
{
  __shared__ __align__(16) unsigned char smem[81920];
  const int t = threadIdx.x;
  const int lane = t & 63;
  const int w = t >> 6;
  const int g = lane >> 4;
  const int ln = lane & 15;
  const int wm = w & 3;
  const int wn = w >> 2;

  const int orig = blockIdx.x;
  const int wg = (orig & 7) * 768 + (orig >> 3);
  const int h = wg % 12;
  const int bn = wg / 12;

  const float* xw = x + (size_t)bn * (WT * DM);
  const unsigned char* whead = wimg + (size_t)h * (24 * W1CH);

  f32x4 acc[2][6];
#pragma unroll
  for (int i = 0; i < 2; ++i)
#pragma unroll
    for (int j = 0; j < 6; ++j) acc[i][j] = (f32x4){0.f, 0.f, 0.f, 0.f};

  const int exr = wm * 32 + (lane & 31);
  const int exs = wn * 2 + (lane >> 5);
  const float* xptr = xw + (size_t)exr * DM + wn * 16 + (lane >> 5) * 8;
  const int ex_w_hi = exr * 128 + ((exs ^ (exr & 7)) << 4);
  const int ex_w_lo = exr * 128 + (((exs + 4) ^ (exr & 7)) << 4);
  int ex_r_h[2], ex_r_l[2];
#pragma unroll
  for (int sm = 0; sm < 2; ++sm) {
    int rr = wm * 32 + sm * 16 + ln;
    ex_r_h[sm] = rr * 128 + ((g ^ (rr & 7)) << 4);
    ex_r_l[sm] = rr * 128 + (((g + 4) ^ (rr & 7)) << 4);
  }

  {
    gl_lds16(whead + t * 16, smem + t * 16);
    if (t < 256) gl_lds16(whead + 8192 + t * 16, smem + 8192 + t * 16);
  }
  __builtin_amdgcn_sched_barrier(0);
  float4 xa = *(const float4*)xptr;
  float4 xb = *(const float4*)(xptr + 4);
  __builtin_amdgcn_sched_barrier(0);

  for (int c = 0; c < 24; ++c) {
    float4 na, nb;
    if (c < 23) {
      na = *(const float4*)(xptr + (c + 1) * 32);
      nb = *(const float4*)(xptr + (c + 1) * 32 + 4);
    }
    __builtin_amdgcn_sched_barrier(0);
    bf16x8 xh8, xl8;
    split8(xa, xb, xh8, xl8);
    unsigned char* exb = smem + EX_OFF + (c & 1) * 16384;
    *(bf16x8*)(exb + ex_w_hi) = xh8;
    *(bf16x8*)(exb + ex_w_lo) = xl8;
    __builtin_amdgcn_sched_barrier(0);
    if (c < 23) asm volatile("s_waitcnt vmcnt(2)" ::: "memory");
    else        asm volatile("s_waitcnt vmcnt(0)" ::: "memory");
    asm volatile("s_waitcnt lgkmcnt(0)" ::: "memory");
    __builtin_amdgcn_s_barrier();
    __builtin_amdgcn_sched_barrier(0);
    if (c < 23) {
      const unsigned char* src = whead + (size_t)(c + 1) * W1CH;
      unsigned char* dst = smem + ((c + 1) & 1) * W1CH;
      gl_lds16(src + t * 16, dst + t * 16);
      if (t < 256) gl_lds16(src + 8192 + t * 16, dst + 8192 + t * 16);
    }
    __builtin_amdgcn_sched_barrier(0);
    const unsigned char* WH = smem + (c & 1) * W1CH;
    bf16x8 ah0 = *(const bf16x8*)(exb + ex_r_h[0]);
    bf16x8 al0 = *(const bf16x8*)(exb + ex_r_l[0]);
    bf16x8 ah1 = *(const bf16x8*)(exb + ex_r_h[1]);
    bf16x8 al1 = *(const bf16x8*)(exb + ex_r_l[1]);
    __builtin_amdgcn_s_setprio(1);
#pragma unroll
    for (int ns = 0; ns < 6; ++ns) {
      int j = (ns * 2 + wn) * 16 + ln;
      int sw = j * 64 + ((g ^ ((j >> 1) & 3)) << 4);
      bf16x8 bh = *(const bf16x8*)(WH + sw);
      acc[0][ns] = __builtin_amdgcn_mfma_f32_16x16x32_bf16(ah0, bh, acc[0][ns], 0, 0, 0);
      acc[1][ns] = __builtin_amdgcn_mfma_f32_16x16x32_bf16(ah1, bh, acc[1][ns], 0, 0, 0);
      if (ns < 4) {
        acc[0][ns] = __builtin_amdgcn_mfma_f32_16x16x32_bf16(al0, bh, acc[0][ns], 0, 0, 0);
        acc[1][ns] = __builtin_amdgcn_mfma_f32_16x16x32_bf16(al1, bh, acc[1][ns], 0, 0, 0);
      }
    }
    __builtin_amdgcn_s_setprio(0);
    xa = na; xb = nb;
  }
  __syncthreads();

#pragma unroll
  for (int ns = 0; ns < 6; ++ns) {
    int cc = (ns * 2 + wn) * 16 + ln;
    int sec = cc >> 6, dd = cc & 63;
    float bias = qkv_b[sec * DM + h * 64 + dd];
#pragma unroll
    for (int sm = 0; sm < 2; ++sm) {
#pragma unroll
      for (int r = 0; r < 4; ++r) {
        int m = wm * 32 + sm * 16 + 4 * g + r;
        float val = acc[sm][ns][r] + bias;
        if (cc < 64) {
          val *= 0.125f;
          unsigned short hi, lo; bf_split_fast(val, hi, lo);
          int byte = m * 128 + (((dd >> 3) ^ (m & 7)) << 4) + ((dd & 7) << 1);
          *(unsigned short*)(smem + QH_OFF + byte) = hi;
          *(unsigned short*)(smem + QL_OFF + byte) = lo;
        } else if (cc < 128) {
          unsigned short hi, lo; bf_split_fast(val, hi, lo);
          int byte = m * 128 + (((dd >> 3) ^ (m & 7)) << 4) + ((dd & 7) << 1);
          *(unsigned short*)(smem + KH_OFF + byte) = hi;
          *(unsigned short*)(smem + KL_OFF + byte) = lo;
        } else {
          int byte = dd * 256 + ((((m >> 3) ^ (dd & 15))) << 4) + ((m & 7) << 1);
          *(unsigned short*)(smem + VT_OFF + byte) = bf_rne_fast(val);
        }
      }
    }
  }
  __syncthreads();

  const int mB = w * 16;
  f32x4 s2[8];
#pragma unroll
  for (int ns = 0; ns < 8; ++ns) s2[ns] = (f32x4){0.f, 0.f, 0.f, 0.f};
#pragma unroll
  for (int ks = 0; ks < 2; ++ks) {
    int arow = mB + ln;
    int abyte = arow * 128 + (((ks * 4 + g) ^ (arow & 7)) << 4);
    bf16x8 qh = *(const bf16x8*)(smem + QH_OFF + abyte);
    bf16x8 ql = *(const bf16x8*)(smem + QL_OFF + abyte);
#pragma unroll
    for (int ns = 0; ns < 8; ++ns) {
      int brow = ns * 16 + ln;
      int bbyte = brow * 128 + (((ks * 4 + g) ^ (brow & 7)) << 4);
      bf16x8 kh = *(const bf16x8*)(smem + KH_OFF + bbyte);
      bf16x8 kl = *(const bf16x8*)(smem + KL_OFF + bbyte);
      s2[ns] = __builtin_amdgcn_mfma_f32_16x16x32_bf16(qh, kh, s2[ns], 0, 0, 0);
      s2[ns] = __builtin_amdgcn_mfma_f32_16x16x32_bf16(qh, kl, s2[ns], 0, 0, 0);
      s2[ns] = __builtin_amdgcn_mfma_f32_16x16x32_bf16(ql, kh, s2[ns], 0, 0, 0);
    }
  }
  __syncthreads();

  const float* mk = mask + (size_t)(bn & 127) * (WT * WT);
  const float* eb = edge_bias + (size_t)h * (WT * WT);
#pragma unroll
  for (int r = 0; r < 4; ++r) {
    int m = mB + 4 * g + r;
    float sv[8];
#pragma unroll
    for (int ns = 0; ns < 8; ++ns) sv[ns] = s2[ns][r];
    float m1 = sv[0];
#pragma unroll
    for (int ns = 1; ns < 8; ++ns) m1 = fmaxf(m1, sv[ns]);
#pragma unroll
    for (int off = 1; off < 16; off <<= 1) m1 = fmaxf(m1, __shfl_xor(m1, off, 64));
    float e[8], sum1 = 0.f;
#pragma unroll
    for (int ns = 0; ns < 8; ++ns) { e[ns] = __expf(sv[ns] - m1); sum1 += e[ns]; }
#pragma unroll
    for (int off = 1; off < 16; off <<= 1) sum1 += __shfl_xor(sum1, off, 64);
    float thr = 0.5f * sum1;
    float tv[8];
#pragma unroll
    for (int ns = 0; ns < 8; ++ns) {
      int col = ns * 16 + ln;
      float mkv = mk[m * WT + col];
      float ebv = eb[m * WT + col];
      float keep = (e[ns] > thr) ? 0.f : 1.f;
      float val = sv[ns] * keep * mkv * ebv;
      tv[ns] = (val == 0.f) ? -10000.f : val;
    }
    float m2 = tv[0];
#pragma unroll
    for (int ns = 1; ns < 8; ++ns) m2 = fmaxf(m2, tv[ns]);
#pragma unroll
    for (int off = 1; off < 16; off <<= 1) m2 = fmaxf(m2, __shfl_xor(m2, off, 64));
    float e2[8], sum2 = 0.f;
#pragma unroll
    for (int ns = 0; ns < 8; ++ns) { e2[ns] = __expf(tv[ns] - m2); sum2 += e2[ns]; }
#pragma unroll
    for (int off = 1; off < 16; off <<= 1) sum2 += __shfl_xor(sum2, off, 64);
    float inv = 1.f / sum2;
#pragma unroll
    for (int ns = 0; ns < 8; ++ns)
      *(unsigned short*)(smem + P_OFF + m * 272 + (ns * 16 + ln) * 2) = bf_rne_fast(e2[ns] * inv);
  }
  __syncthreads();

  f32x4 o4[4];
#pragma unroll
  for (int ns = 0; ns < 4; ++ns) o4[ns] = (f32x4){0.f, 0.f, 0.f, 0.f};
#pragma unroll
  for (int ks = 0; ks < 4; ++ks) {
    bf16x8 pa = *(const bf16x8*)(smem + P_OFF + (mB + ln) * 272 + ks * 64 + g * 16);
#pragma unroll
    for (int ns = 0; ns < 4; ++ns) {
      int d = ns * 16 + ln;
      bf16x8 vb = *(const bf16x8*)(smem + VT_OFF + d * 256 + (((ks * 4 + g) ^ (d & 15)) << 4));
      o4[ns] = __builtin_amdgcn_mfma_f32_16x16x32_bf16(pa, vb, o4[ns], 0, 0, 0);
    }
  }
#pragma unroll
  for (int ns = 0; ns < 4; ++ns)
#pragma unroll
    for (int r = 0; r < 4; ++r)
      out[(size_t)bn * (WT * DM) + (size_t)(mB + 4 * g + r) * DM + h * 64 + ns * 16 + ln] = o4[ns][r];
}

// ---------------- proj (PRE path): 64-row blocks, W 3-buf + A 3-buf --------
#define PAOFF 147456

__global__ __launch_bounds__(512) void proj_kernel_pre(
    const float* src, const unsigned char* __restrict__ wimg,
    const float* __restrict__ pb, float* dst)
{
  __shared__ __align__(16) unsigned char smem[159744];
  const int t = threadIdx.x;
  const int lane = t & 63;
  const int w = t >> 6;
  const int g = lane >> 4;
  const int ln = lane & 15;
  const int wm = w & 1;
  const int wn = w >> 1;

  const int orig = blockIdx.x;
  const int wg = (orig & 7) * 128 + (orig >> 3);
  const size_t row0 = (size_t)wg * 64;

  const int ar = t >> 3, ac4 = t & 7;
  const float* asrc = src + (row0 + ar) * DM + ac4 * 4;
  const int abyte = ar * 64 + (((ac4 >> 1) ^ ((ar >> 1) & 3)) << 4) + ((ac4 & 1) << 3);
  int afh[2];
#pragma unroll
  for (int sm = 0; sm < 2; ++sm) {
    int rr = wm * 32 + sm * 16 + ln;
    afh[sm] = rr * 64 + ((g ^ ((rr >> 1) & 3)) << 4);
  }

  {
    const unsigned char* sW = wimg + t * 16;
#pragma unroll
    for (int i = 0; i < 6; ++i) gl_lds16(sW + i * 8192, smem + t * 16 + i * 8192);
    const unsigned char* sW1 = wimg + PWCHUNK + t * 16;
#pragma unroll
    for (int i = 0; i < 6; ++i) gl_lds16(sW1 + i * 8192, smem + PWCHUNK + t * 16 + i * 8192);
  }
  __builtin_amdgcn_sched_barrier(0);
  float4 a0 = *(const float4*)asrc;
  float4 a1 = *(const float4*)(asrc + 32);
  {
    uint2 wv; wv.x = cvt_pk_bf16(a0.x, a0.y); wv.y = cvt_pk_bf16(a0.z, a0.w);
    *(uint2*)(smem + PAOFF + abyte) = wv;
  }
  __builtin_amdgcn_sched_barrier(0);

  f32x4 acc[2][12];
#pragma unroll
  for (int i = 0; i < 2; ++i)
#pragma unroll
    for (int j = 0; j < 12; ++j) acc[i][j] = (f32x4){0.f, 0.f, 0.f, 0.f};

  for (int c = 0; c < 24; ++c) {
    float4 a2;
    if (c < 22) a2 = *(const float4*)(asrc + (c + 2) * 32);
    __builtin_amdgcn_sched_barrier(0);
    if (c < 23) {
      uint2 wv; wv.x = cvt_pk_bf16(a1.x, a1.y); wv.y = cvt_pk_bf16(a1.z, a1.w);
      *(uint2*)(smem + PAOFF + ((c + 1) % 3) * 4096 + abyte) = wv;
    }
    __builtin_amdgcn_sched_barrier(0);
    if (c < 22)       asm volatile("s_waitcnt vmcnt(8)" ::: "memory");
    else if (c == 22) asm volatile("s_waitcnt vmcnt(7)" ::: "memory");
    else              asm volatile("s_waitcnt vmcnt(0)" ::: "memory");
    asm volatile("s_waitcnt lgkmcnt(0)" ::: "memory");
    __builtin_amdgcn_s_barrier();
    __builtin_amdgcn_sched_barrier(0);
    if (c < 22) {
      const unsigned char* sW = wimg + (size_t)(c + 2) * PWCHUNK + t * 16;
      unsigned char* dW = smem + ((c + 2) % 3) * PWCHUNK + t * 16;
#pragma unroll
      for (int i = 0; i < 6; ++i) gl_lds16(sW + i * 8192, dW + i * 8192);
    }
    __builtin_amdgcn_sched_barrier(0);
    const unsigned char* WB = smem + (c % 3) * PWCHUNK;
    const unsigned char* AB = smem + PAOFF + (c % 3) * 4096;
    bf16x8 af0 = *(const bf16x8*)(AB + afh[0]);
    bf16x8 af1 = *(const bf16x8*)(AB + afh[1]);
    __builtin_amdgcn_s_setprio(1);
#pragma unroll
    for (int ns = 0; ns < 12; ++ns) {
      int n = wn * 192 + ns * 16 + ln;
      bf16x8 bfrag = *(const bf16x8*)(WB + n * 64 + ((g ^ ((n >> 1) & 3)) << 4));
      acc[0][ns] = __builtin_amdgcn_mfma_f32_16x16x32_bf16(af0, bfrag, acc[0][ns], 0, 0, 0);
      acc[1][ns] = __builtin_amdgcn_mfma_f32_16x16x32_bf16(af1, bfrag, acc[1][ns], 0, 0, 0);
    }
    __builtin_amdgcn_s_setprio(0);
    a1 = a2;
  }

#pragma unroll
  for (int ns = 0; ns < 12; ++ns) {
    int col = wn * 192 + ns * 16 + ln;
    float pbv = pb[col];
#pragma unroll
    for (int sm = 0; sm < 2; ++sm)
#pragma unroll
      for (int r = 0; r < 4; ++r)
        dst[(row0 + wm * 32 + sm * 16 + 4 * g + r) * DM + col] = acc[sm][ns][r] + pbv;
  }
}

// ---------------- proj fallback (no-ws path) ------------------------------
#define PA_OFF 0
#define PW_OFF 98304

__global__ __launch_bounds__(512, 2) void proj_kernel_fb(
    const float* src, const float* __restrict__ pw,
    const float* __restrict__ pb, float* dst)
{
  __shared__ __align__(16) unsigned char smem[147456];
  const int t = threadIdx.x;
  const int lane = t & 63;
  const int w = t >> 6;
  const int g = lane >> 4;
  const int ln = lane & 15;
  const int wm = w & 1;
  const int wn = w >> 1;

  const int orig = blockIdx.x;
  const int wg = (orig & 7) * 128 + (orig >> 3);
  const size_t row0 = (size_t)wg * 64;

#pragma unroll
  for (int q = 0; q < 24; ++q) {
    int fid = q * 512 + t;
    int row = fid / 192, c4 = fid % 192;
    float4 v = *(const float4*)(src + (row0 + row) * DM + c4 * 4);
    int slot = c4 >> 1;
    int byte = row * 1536 + (((slot & ~7) | ((slot & 7) ^ (row & 7))) << 4) + ((c4 & 1) << 3);
    uint2 hv;
    hv.x = (unsigned)bf_rne(v.x) | ((unsigned)bf_rne(v.y) << 16);
    hv.y = (unsigned)bf_rne(v.z) | ((unsigned)bf_rne(v.w) << 16);
    *(uint2*)(smem + PA_OFF + byte) = hv;
  }

  f32x4 accp[2][12];
#pragma unroll
  for (int i = 0; i < 2; ++i)
#pragma unroll
    for (int j = 0; j < 12; ++j) accp[i][j] = (f32x4){0.f, 0.f, 0.f, 0.f};

  for (int c = 0; c < 24; ++c) {
    const int kc = c * 32;
    __syncthreads();
#pragma unroll
    for (int q = 0; q < 12; ++q) {
      int fid = q * 512 + t;
      int n = fid >> 3, c4 = fid & 7;
      float4 v = *(const float4*)(pw + (size_t)n * DM + kc + c4 * 4);
      int slot = (n & 1) * 4 + (c4 >> 1);
      int byte = (n >> 1) * 128 + ((slot ^ ((n >> 1) & 7)) << 4) + ((c4 & 1) << 3);
      uint2 hv;
      hv.x = (unsigned)bf_rne(v.x) | ((unsigned)bf_rne(v.y) << 16);
      hv.y = (unsigned)bf_rne(v.z) | ((unsigned)bf_rne(v.w) << 16);
      *(uint2*)(smem + PW_OFF + byte) = hv;
    }
    __syncthreads();
    bf16x8 af[2];
#pragma unroll
    for (int sm = 0; sm < 2; ++sm) {
      int row = wm * 32 + sm * 16 + ln;
      int slot = (kc >> 3) + g;
      int byte = row * 1536 + (((slot & ~7) | ((slot & 7) ^ (row & 7))) << 4);
      af[sm] = *(const bf16x8*)(smem + PA_OFF + byte);
    }
#pragma unroll
    for (int j = 0; j < 12; ++j) {
      int n = (wn * 12 + j) * 16 + ln;
      int slot = (n & 1) * 4 + g;
      bf16x8 bf_ = *(const bf16x8*)(smem + PW_OFF + (n >> 1) * 128 + ((slot ^ ((n >> 1) & 7)) << 4));
#pragma unroll
      for (int sm = 0; sm < 2; ++sm)
        accp[sm][j] = __builtin_amdgcn_mfma_f32_16x16x32_bf16(af[sm], bf_, accp[sm][j], 0, 0, 0);
    }
  }

#pragma unroll
  for (int j = 0; j < 12; ++j) {
    int col = (wn * 12 + j) * 16 + ln;
    float pbv = pb[col];
#pragma unroll
    for (int sm = 0; sm < 2; ++sm)
#pragma unroll
      for (int r = 0; r < 4; ++r)
        dst[(row0 + wm * 32 + sm * 16 + 4 * g + r) * DM + col] = accp[sm][j][r] + pbv;
  }
}

// ---------------- attn fallback (no-ws path, round-2 verified) -------------
__global__ __launch_bounds__(512, 2) void attn_kernel_fb(
    const float* __restrict__ x, const float* __restrict__ qkv_w,
    const float* __restrict__ qkv_b, const float* __restrict__ edge_bias,
    const float* __restrict__ mask, float* __restrict__ out)
{
  __shared__ __align__(16) unsigned char smem[98304];
  const int t = threadIdx.x;
  const int lane = t & 63;
  const int w = t >> 6;
  const int g = lane >> 4;
  const int ln = lane & 15;
  const int wm = w & 3;
  const int wn = w >> 2;

  const int orig = blockIdx.x;
  const int wg = (orig & 7) * 768 + (orig >> 3);
  const int h = wg % 12;
  const int bn = wg / 12;

  const float* xw = x + (size_t)bn * (WT * DM);

  f32x4 acc[2][6];
#pragma unroll
  for (int i = 0; i < 2; ++i)
#pragma unroll
    for (int j = 0; j < 6; ++j) acc[i][j] = (f32x4){0.f, 0.f, 0.f, 0.f};

  float4 wreg[6], xreg[8];
#pragma unroll
  for (int q = 0; q < 6; ++q) {
    int fid = q * 512 + t;
    int j = fid >> 4, c4 = fid & 15;
    int sec = j >> 6, d = j & 63;
    wreg[q] = *(const float4*)(qkv_w + (size_t)(sec * DM + h * 64 + d) * DM + c4 * 4);
  }

  for (int c = 0; c < 12; ++c) {
    const int kc = c * 64;
#pragma unroll
    for (int sm = 0; sm < 2; ++sm)
#pragma unroll
      for (int ks = 0; ks < 2; ++ks) {
        int row = wm * 32 + sm * 16 + ln;
        const float* p = xw + (size_t)row * DM + kc + ks * 32 + g * 8;
        xreg[(sm * 2 + ks) * 2 + 0] = *(const float4*)p;
        xreg[(sm * 2 + ks) * 2 + 1] = *(const float4*)(p + 4);
      }
    unsigned char* WH = smem + (c & 1) * 49152;
    unsigned char* WL = WH + 24576;
#pragma unroll
    for (int q = 0; q < 6; ++q) {
      int fid = q * 512 + t;
      int j = fid >> 4, c4 = fid & 15;
      int byte = j * 128 + ((((c4 >> 1) ^ (j & 7))) << 4) + ((c4 & 1) << 3);
      float4 v = wreg[q];
      unsigned short h0, h1, h2, h3, l0, l1, l2, l3;
      bf_split(v.x, h0, l0); bf_split(v.y, h1, l1);
      bf_split(v.z, h2, l2); bf_split(v.w, h3, l3);
      uint2 hv, lv;
      hv.x = (unsigned)h0 | ((unsigned)h1 << 16); hv.y = (unsigned)h2 | ((unsigned)h3 << 16);
      lv.x = (unsigned)l0 | ((unsigned)l1 << 16); lv.y = (unsigned)l2 | ((unsigned)l3 << 16);
      *(uint2*)(WH + byte) = hv;
      *(uint2*)(WL + byte) = lv;
    }
    if (c < 11) {
#pragma unroll
      for (int q = 0; q < 6; ++q) {
        int fid = q * 512 + t;
        int j = fid >> 4, c4 = fid & 15;
        int sec = j >> 6, d = j & 63;
        wreg[q] = *(const float4*)(qkv_w + (size_t)(sec * DM + h * 64 + d) * DM + kc + 64 + c4 * 4);
      }
    }
    __syncthreads();
#pragma unroll
    for (int ks = 0; ks < 2; ++ks) {
      bf16x8 ah[2], al[2];
#pragma unroll
      for (int sm = 0; sm < 2; ++sm)
        split8(xreg[(sm * 2 + ks) * 2 + 0], xreg[(sm * 2 + ks) * 2 + 1], ah[sm], al[sm]);
#pragma unroll
      for (int ns = 0; ns < 6; ++ns) {
        int j = wn * 96 + ns * 16 + ln;
        int sw = j * 128 + (((ks * 4 + g) ^ (j & 7)) << 4);
        bf16x8 bh = *(const bf16x8*)(WH + sw);
        bf16x8 bl = *(const bf16x8*)(WL + sw);
#pragma unroll
        for (int sm = 0; sm < 2; ++sm) {
          acc[sm][ns] = __builtin_amdgcn_mfma_f32_16x16x32_bf16(ah[sm], bh, acc[sm][ns], 0, 0, 0);
          acc[sm][ns] = __builtin_amdgcn_mfma_f32_16x16x32_bf16(ah[sm], bl, acc[sm][ns], 0, 0, 0);
          acc[sm][ns] = __builtin_amdgcn_mfma_f32_16x16x32_bf16(al[sm], bh, acc[sm][ns], 0, 0, 0);
        }
      }
    }
  }
  __syncthreads();

#pragma unroll
  for (int sm = 0; sm < 2; ++sm)
#pragma unroll
    for (int ns = 0; ns < 6; ++ns) {
      int cc = wn * 96 + ns * 16 + ln;
      int sec = cc >> 6, dd = cc & 63;
      float bias = qkv_b[sec * DM + h * 64 + dd];
#pragma unroll
      for (int r = 0; r < 4; ++r) {
        int m = wm * 32 + sm * 16 + 4 * g + r;
        float val = acc[sm][ns][r] + bias;
        if (cc < 64) {
          val *= 0.125f;
          unsigned short hi, lo; bf_split(val, hi, lo);
          int byte = m * 128 + ((((dd >> 3) ^ (m & 7))) << 4) + ((dd & 7) << 1);
          *(unsigned short*)(smem + QH_OFF + byte) = hi;
          *(unsigned short*)(smem + QL_OFF + byte) = lo;
        } else if (cc < 128) {
          unsigned short hi, lo; bf_split(val, hi, lo);
          int byte = m * 128 + ((((dd >> 3) ^ (m & 7))) << 4) + ((dd & 7) << 1);
          *(unsigned short*)(smem + KH_OFF + byte) = hi;
          *(unsigned short*)(smem + KL_OFF + byte) = lo;
        } else {
          *(unsigned short*)(smem + VT_OFF + dd * 272 + m * 2) = bf_rne(val);
        }
      }
    }
  __syncthreads();

  const int mB = w * 16;
  f32x4 s2[8];
#pragma unroll
  for (int ns = 0; ns < 8; ++ns) s2[ns] = (f32x4){0.f, 0.f, 0.f, 0.f};
#pragma unroll
  for (int ks = 0; ks < 2; ++ks) {
    int arow = mB + ln;
    int abyte = arow * 128 + (((ks * 4 + g) ^ (arow & 7)) << 4);
    bf16x8 qh = *(const bf16x8*)(smem + QH_OFF + abyte);
    bf16x8 ql = *(const bf16x8*)(smem + QL_OFF + abyte);
#pragma unroll
    for (int ns = 0; ns < 8; ++ns) {
      int brow = ns * 16 + ln;
      int bbyte = brow * 128 + (((ks * 4 + g) ^ (brow & 7)) << 4);
      bf16x8 kh = *(const bf16x8*)(smem + KH_OFF + bbyte);
      bf16x8 kl = *(const bf16x8*)(smem + KL_OFF + bbyte);
      s2[ns] = __builtin_amdgcn_mfma_f32_16x16x32_bf16(qh, kh, s2[ns], 0, 0, 0);
      s2[ns] = __builtin_amdgcn_mfma_f32_16x16x32_bf16(qh, kl, s2[ns], 0, 0, 0);
      s2[ns] = __builtin_amdgcn_mfma_f32_16x16x32_bf16(ql, kh, s2[ns], 0, 0, 0);
    }
  }
  __syncthreads();

  const float* mk = mask + (size_t)(bn & 127) * (WT * WT);
  const float* eb = edge_bias + (size_t)h * (WT * WT);
#pragma unroll
  for (int r = 0; r < 4; ++r) {
    int m = mB + 4 * g + r;
    float sv[8];
#pragma unroll
    for (int ns = 0; ns < 8; ++ns) sv[ns] = s2[ns][r];
    float m1 = sv[0];
#pragma unroll
    for (int ns = 1; ns < 8; ++ns) m1 = fmaxf(m1, sv[ns]);
#pragma unroll
    for (int off = 1; off < 16; off <<= 1) m1 = fmaxf(m1, __shfl_xor(m1, off, 64));
    float e[8], sum1 = 0.f;
#pragma unroll
    for (int ns = 0; ns < 8; ++ns) { e[ns] = __expf(sv[ns] - m1); sum1 += e[ns]; }
#pragma unroll
    for (int off = 1; off < 16; off <<= 1) sum1 += __shfl_xor(sum1, off, 64);
    float thr = 0.5f * sum1;
    float tv[8];
#pragma unroll
    for (int ns = 0; ns < 8; ++ns) {
      int col = ns * 16 + ln;
      float mkv = mk[m * WT + col];
      float ebv = eb[m * WT + col];
      float keep = (e[ns] > thr) ? 0.f : 1.f;
      float val = sv[ns] * keep * mkv * ebv;
      tv[ns] = (val == 0.f) ? -10000.f : val;
    }
    float m2 = tv[0];
#pragma unroll
    for (int ns = 1; ns < 8; ++ns) m2 = fmaxf(m2, tv[ns]);
#pragma unroll
    for (int off = 1; off < 16; off <<= 1) m2 = fmaxf(m2, __shfl_xor(m2, off, 64));
    float e2[8], sum2 = 0.f;
#pragma unroll
    for (int ns = 0; ns < 8; ++ns) { e2[ns] = __expf(tv[ns] - m2); sum2 += e2[ns]; }
#pragma unroll
    for (int off = 1; off < 16; off <<= 1) sum2 += __shfl_xor(sum2, off, 64);
    float inv = 1.f / sum2;
#pragma unroll
    for (int ns = 0; ns < 8; ++ns)
      *(unsigned short*)(smem + P_OFF + m * 272 + (ns * 16 + ln) * 2) = bf_rne(e2[ns] * inv);
  }
  __syncthreads();

  f32x4 o4[4];
#pragma unroll
  for (int ns = 0; ns < 4; ++ns) o4[ns] = (f32x4){0.f, 0.f, 0.f, 0.f};
#pragma unroll
  for (int ks = 0; ks < 4; ++ks) {
    bf16x8 pa = *(const bf16x8*)(smem + P_OFF + (mB + ln) * 272 + ks * 64 + g * 16);
#pragma unroll
    for (int ns = 0; ns < 4; ++ns) {
      bf16x8 vb = *(const bf16x8*)(smem + VT_OFF + (ns * 16 + ln) * 272 + ks * 64 + g * 16);
      o4[ns] = __builtin_amdgcn_mfma_f32_16x16x32_bf16(pa, vb, o4[ns], 0, 0, 0);
    }
  }
#pragma unroll
  for (int ns = 0; ns < 4; ++ns)
#pragma unroll
    for (int r = 0; r < 4; ++r)
      out[(size_t)bn * (WT * DM) + (size_t)(mB + 4 * g + r) * DM + h * 64 + ns * 16 + ln] = o4[ns][r];
}

extern "C" void kernel_launch(void* const* d_in, const int* in_sizes, int n_in,
                              void* d_out, int out_size, void* d_ws, size_t ws_size,
                              hipStream_t stream) {
  const float* x         = (const float*)d_in[0];
  const float* qkv_w     = (const float*)d_in[1];
  const float* qkv_b     = (const float*)d_in[2];
  const float* proj_w    = (const float*)d_in[3];
  const float* proj_b    = (const float*)d_in[4];
  const float* edge_bias = (const float*)d_in[5];
  const float* mask      = (const float*)d_in[6];
  float* out = (float*)d_out;

  const bool p1 = (d_ws != nullptr) && (ws_size >= WS_W1);
  const bool p2 = (d_ws != nullptr) && (ws_size >= WS_W1 + WS_W2);
  unsigned char* wsW = (unsigned char*)d_ws;
  unsigned char* wsP = wsW + WS_W1;
  unsigned char* wsA = wsP + WS_W2;

  // split-path batch count: 4 batches (126MB, L3-resident) preferred, else 8
  const size_t base = WS_W1 + WS_W2;
  int nb = 0;
  if (p2 && ws_size >= base + (size_t)64 * 24 * IMG_SZ)      nb = 4;
  else if (p2 && ws_size >= base + (size_t)32 * 24 * IMG_SZ) nb = 8;

  if (p1) split_w_kernel<<<1728, 256, 0, stream>>>(qkv_w, wsW);
  if (p2) split_pw_kernel<<<576, 256, 0, stream>>>(proj_w, wsP);

  if (nb) {
    const int pb = 256 / nb;   // window-pairs per batch
    for (int b = 0; b < nb; ++b) {
      qkv2_kernel<<<pb * 12, 512, 0, stream>>>(x, wsW, qkv_b, wsA, b * pb);
      attn2_kernel<<<pb * 24, 512, 0, stream>>>(wsA, edge_bias, mask, out, b * pb * 2);
    }
  } else if (p1) {
    attn_kernel_pre<<<NW * NH, 512, 0, stream>>>(x, wsW, qkv_b, edge_bias, mask, out);
  } else {
    attn_kernel_fb<<<NW * NH, 512, 0, stream>>>(x, qkv_w, qkv_b, edge_bias, mask, out);
  }

  if (p2) {
    proj_kernel_pre<<<1024, 512, 0, stream>>>(out, wsP, proj_b, out);
  } else {
    proj_kernel_fb<<<1024, 512, 0, stream>>>(out, proj_w, proj_b, out);
  }
}

// Round 11
// 891.149 us; speedup vs baseline: 1.0106x; 1.0106x over previous
//
#include <hip/hip_runtime.h>

#define NW 512
#define WT 128
#define DM 768
#define NH 12

typedef __attribute__((ext_vector_type(8))) short bf16x8;
typedef __attribute__((ext_vector_type(4))) float f32x4;
typedef __attribute__((ext_vector_type(4))) unsigned int u32x4;

#define W1CH 12288                            // one (head,chunk) attn W image (single bf16)
#define WS_W1 ((size_t)NH * 24 * W1CH)        // 3,538,944 attn W images
#define PWCHUNK 49152                         // one proj W k32 chunk image
#define WS_W2 ((size_t)24 * PWCHUNK)          // 1,179,648 proj W image
#define IMG_SZ 81920                          // per-(window,head) q/k/v image

__device__ __forceinline__ unsigned short bf_rne(float v) {
  unsigned u = __float_as_uint(v);
  unsigned r = u + 0x7fffu + ((u >> 16) & 1u);
  return (unsigned short)(r >> 16);
}
__device__ __forceinline__ void bf_split(float v, unsigned short& hi, unsigned short& lo) {
  hi = bf_rne(v);
  float hf = __uint_as_float(((unsigned)hi) << 16);
  lo = bf_rne(v - hf);
}

__device__ __forceinline__ unsigned cvt_pk_bf16(float a, float b) {
  unsigned r;
  asm("v_cvt_pk_bf16_f32 %0, %1, %2" : "=v"(r) : "v"(a), "v"(b));
  return r;
}
__device__ __forceinline__ unsigned short bf_rne_fast(float v) {
  return (unsigned short)cvt_pk_bf16(v, v);
}
__device__ __forceinline__ void bf_split_fast(float v, unsigned short& hi, unsigned short& lo) {
  unsigned hp = cvt_pk_bf16(v, v);
  float hf = __uint_as_float(hp << 16);
  lo = (unsigned short)cvt_pk_bf16(v - hf, v - hf);
  hi = (unsigned short)hp;
}

__device__ __forceinline__ void split8(float4 v0, float4 v1, bf16x8& hi, bf16x8& lo) {
  float f[8] = {v0.x, v0.y, v0.z, v0.w, v1.x, v1.y, v1.z, v1.w};
  u32x4 hu, lu;
#pragma unroll
  for (int i = 0; i < 4; ++i) {
    float e0 = f[2 * i], e1 = f[2 * i + 1];
    unsigned hp = cvt_pk_bf16(e0, e1);
    float h0 = __uint_as_float(hp << 16);
    float h1 = __uint_as_float(hp & 0xffff0000u);
    lu[i] = cvt_pk_bf16(e0 - h0, e1 - h1);
    hu[i] = hp;
  }
  hi = __builtin_bit_cast(bf16x8, hu);
  lo = __builtin_bit_cast(bf16x8, lu);
}

__device__ __forceinline__ void gl_lds16(const void* g, void* l) {
  __builtin_amdgcn_global_load_lds(
      (const __attribute__((address_space(1))) void*)g,
      (__attribute__((address_space(3))) void*)l, 16, 0, 0);
}
__device__ __forceinline__ void gl_lds4(const void* g, void* l) {
  __builtin_amdgcn_global_load_lds(
      (const __attribute__((address_space(1))) void*)g,
      (__attribute__((address_space(3))) void*)l, 4, 0, 0);
}

// ---------------- precompute: attn W -> single-bf16 swizzled LDS images ----
__global__ __launch_bounds__(256) void split_w_kernel(
    const float* __restrict__ qkv_w, unsigned char* __restrict__ wsW)
{
  int id = blockIdx.x * 256 + threadIdx.x;
  int c4 = id & 7;
  int j  = (id >> 3) % 192;
  int hc = (id >> 3) / 192;
  int c  = hc % 24;
  int h  = hc / 24;
  int sec = j >> 6, d = j & 63;
  const float* src = qkv_w + (size_t)(sec * DM + h * 64 + d) * DM + c * 32 + c4 * 4;
  float4 v = *(const float4*)src;
  uint2 hv;
  hv.x = (unsigned)bf_rne(v.x) | ((unsigned)bf_rne(v.y) << 16);
  hv.y = (unsigned)bf_rne(v.z) | ((unsigned)bf_rne(v.w) << 16);
  int byte = j * 64 + (((c4 >> 1) ^ ((j >> 1) & 3)) << 4) + ((c4 & 1) << 3);
  *(uint2*)(wsW + (size_t)hc * W1CH + byte) = hv;
}

// ---------------- precompute: proj W -> bf16 swizzled LDS image ------------
__global__ __launch_bounds__(256) void split_pw_kernel(
    const float* __restrict__ pw, unsigned char* __restrict__ wsP)
{
  int id = blockIdx.x * 256 + threadIdx.x;
  int c4 = id & 7;
  int n  = (id >> 3) % 768;
  int c  = (id >> 3) / 768;
  float4 v = *(const float4*)(pw + (size_t)n * DM + c * 32 + c4 * 4);
  uint2 hv;
  hv.x = (unsigned)bf_rne(v.x) | ((unsigned)bf_rne(v.y) << 16);
  hv.y = (unsigned)bf_rne(v.z) | ((unsigned)bf_rne(v.w) << 16);
  int byte = n * 64 + (((c4 >> 1) ^ ((n >> 1) & 3)) << 4) + ((c4 & 1) << 3);
  *(uint2*)(wsP + (size_t)c * PWCHUNK + byte) = hv;
}

// ---- shared image offsets (smem layout AND per-(window,head) ws image) ----
#define QH_OFF 0
#define QL_OFF 16384
#define KH_OFF 32768
#define KL_OFF 49152
#define VT_OFF 65536
#define EX_OFF 49152
#define P_OFF  0

// ================= SPLIT PATH K1: qkv GEMM, 2 windows/block ================
// M=256 (2 windows), N=192; wave w: window w>>2, rows (w&3)*32..+32, all 12
// n-strips -> 40 MFMA/wave/chunk. x direct-to-reg depth-2 unconditional
// clamped prefetch; W dbuf 2x12KB. Epilogue: LDS-transpose then COALESCED
// 16B global stores of the swizzled q(hi/lo)/k(hi/lo)/vT image.
__global__ __launch_bounds__(512, 2) void qkv2_kernel(
    const float* __restrict__ x, const unsigned char* __restrict__ wimg,
    const float* __restrict__ qkv_b, unsigned char* __restrict__ att, int p0)
{
  __shared__ __align__(16) unsigned char smem[32768];   // W dbuf 24K / scratch 32K
  const int t = threadIdx.x;
  const int lane = t & 63;
  const int w = t >> 6;
  const int g = lane >> 4;
  const int ln = lane & 15;
  const int wm = w & 3;
  const int win = w >> 2;

  const int nwg = gridDim.x;
  const int orig = blockIdx.x;
  const int wg = (orig & 7) * (nwg >> 3) + (orig >> 3);
  const int h = wg % 12;
  const int lp = wg / 12;
  const int bn = 2 * (p0 + lp) + win;

  const float* xw = x + (size_t)bn * (WT * DM);
  const unsigned char* whead = wimg + (size_t)h * (24 * W1CH);

  f32x4 acc[2][12];
#pragma unroll
  for (int i = 0; i < 2; ++i)
#pragma unroll
    for (int j = 0; j < 12; ++j) acc[i][j] = (f32x4){0.f, 0.f, 0.f, 0.f};

  const float* xp0 = xw + (size_t)(wm * 32 + ln) * DM + g * 8;
  const float* xp1 = xp0 + (size_t)16 * DM;

  auto stageW = [&](int c, int buf) {
    const unsigned char* s = whead + (size_t)c * W1CH + w * 1536;
    unsigned char* d = smem + buf * W1CH + w * 1536;
    gl_lds16(s + lane * 16, d + lane * 16);
    gl_lds4(s + 1024 + lane * 4, d + 1024 + lane * 4);
    gl_lds4(s + 1280 + lane * 4, d + 1280 + lane * 4);
  };

  stageW(0, 0);
  __builtin_amdgcn_sched_barrier(0);
  float4 xc0 = *(const float4*)xp0;
  float4 xc1 = *(const float4*)(xp0 + 4);
  float4 xc2 = *(const float4*)xp1;
  float4 xc3 = *(const float4*)(xp1 + 4);
  float4 xn0 = *(const float4*)(xp0 + 32);
  float4 xn1 = *(const float4*)(xp0 + 36);
  float4 xn2 = *(const float4*)(xp1 + 32);
  float4 xn3 = *(const float4*)(xp1 + 36);
  __builtin_amdgcn_sched_barrier(0);

  for (int c = 0; c < 24; ++c) {
    // (a) issue x(c+2) UNCONDITIONALLY (clamped -> vmcnt stays exact)
    int cn = (c + 2 < 24 ? c + 2 : 23) * 32;
    float4 nf0 = *(const float4*)(xp0 + cn);
    float4 nf1 = *(const float4*)(xp0 + cn + 4);
    float4 nf2 = *(const float4*)(xp1 + cn);
    float4 nf3 = *(const float4*)(xp1 + cn + 4);
    __builtin_amdgcn_sched_barrier(0);
    // (b) split x(c) (loaded 2 iters ago)
    bf16x8 ah0, al0, ah1, al1;
    split8(xc0, xc1, ah0, al0);
    split8(xc2, xc3, ah1, al1);
    __builtin_amdgcn_sched_barrier(0);
    // (c) retire through W(c); barrier
    asm volatile("s_waitcnt vmcnt(4)" ::: "memory");
    __builtin_amdgcn_s_barrier();
    __builtin_amdgcn_sched_barrier(0);
    // (d) stage W(c+1) (clamped-redundant at tail; idle buffer)
    {
      int cw = (c + 1 < 24 ? c + 1 : 23);
      stageW(cw, (c + 1) & 1);
    }
    __builtin_amdgcn_sched_barrier(0);
    // (e) MFMA on W(c): 12 strips, 2-pass q/k (ns<8), 1-pass v
    const unsigned char* WH = smem + (c & 1) * W1CH;
    __builtin_amdgcn_s_setprio(1);
#pragma unroll
    for (int ns = 0; ns < 12; ++ns) {
      int j = ns * 16 + ln;
      int sw = j * 64 + ((g ^ ((j >> 1) & 3)) << 4);
      bf16x8 bh = *(const bf16x8*)(WH + sw);
      acc[0][ns] = __builtin_amdgcn_mfma_f32_16x16x32_bf16(ah0, bh, acc[0][ns], 0, 0, 0);
      acc[1][ns] = __builtin_amdgcn_mfma_f32_16x16x32_bf16(ah1, bh, acc[1][ns], 0, 0, 0);
      if (ns < 8) {
        acc[0][ns] = __builtin_amdgcn_mfma_f32_16x16x32_bf16(al0, bh, acc[0][ns], 0, 0, 0);
        acc[1][ns] = __builtin_amdgcn_mfma_f32_16x16x32_bf16(al1, bh, acc[1][ns], 0, 0, 0);
      }
    }
    __builtin_amdgcn_s_setprio(0);
    xc0 = xn0; xc1 = xn1; xc2 = xn2; xc3 = xn3;
    xn0 = nf0; xn1 = nf1; xn2 = nf2; xn3 = nf3;
  }

  // drain in-flight DMA (tail stage targets buf0 region = future scratch)
  asm volatile("s_waitcnt vmcnt(0)" ::: "memory");
  __syncthreads();

  // per-lane bias values (one per n-strip)
  float biasv[12];
#pragma unroll
  for (int ns = 0; ns < 12; ++ns) {
    int cc = ns * 16 + ln;
    biasv[ns] = qkv_b[(cc >> 6) * DM + h * 64 + (cc & 63)];
  }

  // epilogue: 5 sections {QH,QL,KH,KL,VT}; scatter->scratch, coalesced copy out
  unsigned char* imgT = att + (((size_t)(lp * 2) * NH + h) * IMG_SZ)
                            + (size_t)(t >> 8) * (NH * IMG_SZ);
  unsigned char* sws = smem + win * 16384;
#pragma unroll
  for (int s5 = 0; s5 < 5; ++s5) {
    if (s5) __syncthreads();          // scratch free (prev copy done)
    const int nsb = (s5 < 2) ? 0 : (s5 < 4) ? 4 : 8;
    const bool isLo = (s5 == 1 || s5 == 3);
    const bool isQ = (s5 <= 1);
    const bool isVT = (s5 == 4);
#pragma unroll
    for (int j = 0; j < 4; ++j) {
      int ns = nsb + j;
      int dd = (ns * 16 + ln) & 63;
      float bias = biasv[ns];
#pragma unroll
      for (int sm = 0; sm < 2; ++sm)
#pragma unroll
        for (int r = 0; r < 4; ++r) {
          int m = wm * 32 + sm * 16 + 4 * g + r;
          float val = acc[sm][ns][r] + bias;
          if (isVT) {
            int byte = dd * 256 + (((m >> 3) ^ (dd & 15)) << 4) + ((m & 7) << 1);
            *(unsigned short*)(sws + byte) = bf_rne_fast(val);
          } else {
            if (isQ) val *= 0.125f;
            unsigned short hi, lo; bf_split_fast(val, hi, lo);
            int byte = m * 128 + (((dd >> 3) ^ (m & 7)) << 4) + ((dd & 7) << 1);
            *(unsigned short*)(sws + byte) = isLo ? lo : hi;
          }
        }
    }
    __syncthreads();                   // scratch ready
    // coalesced copy: threads 0-255 -> window 0 image, 256-511 -> window 1
    const unsigned char* srcp = smem + (t >> 8) * 16384 + (t & 255) * 16;
    unsigned char* dstp = imgT + s5 * 16384 + (t & 255) * 16;
#pragma unroll
    for (int q2 = 0; q2 < 4; ++q2)
      *(u32x4*)(dstp + q2 * 4096) = *(const u32x4*)(srcp + q2 * 4096);
  }
}

// ================= SPLIT PATH K2: attention from staged images =============
__global__ __launch_bounds__(512, 4) void attn2_kernel(
    const unsigned char* __restrict__ att, const float* __restrict__ edge_bias,
    const float* __restrict__ mask, float* __restrict__ out, int w0)
{
  __shared__ __align__(16) unsigned char smem[81920];
  const int t = threadIdx.x;
  const int lane = t & 63;
  const int w = t >> 6;
  const int g = lane >> 4;
  const int ln = lane & 15;

  const int nwg = gridDim.x;
  const int orig = blockIdx.x;
  const int wg = (orig & 7) * (nwg >> 3) + (orig >> 3);
  const int h = wg % 12;
  const int lw = wg / 12;
  const int bn = w0 + lw;

  const unsigned char* img = att + ((size_t)lw * NH + h) * IMG_SZ;
#pragma unroll
  for (int i = 0; i < 10; ++i)
    gl_lds16(img + i * 8192 + t * 16, smem + i * 8192 + t * 16);
  asm volatile("s_waitcnt vmcnt(0)" ::: "memory");
  __syncthreads();

  // ---- Phase B: S = q @ k^T (split 3-pass), wave w owns rows w*16..+16
  const int mB = w * 16;
  f32x4 s2[8];
#pragma unroll
  for (int ns = 0; ns < 8; ++ns) s2[ns] = (f32x4){0.f, 0.f, 0.f, 0.f};
#pragma unroll
  for (int ks = 0; ks < 2; ++ks) {
    int arow = mB + ln;
    int abyte = arow * 128 + (((ks * 4 + g) ^ (arow & 7)) << 4);
    bf16x8 qh = *(const bf16x8*)(smem + QH_OFF + abyte);
    bf16x8 ql = *(const bf16x8*)(smem + QL_OFF + abyte);
#pragma unroll
    for (int ns = 0; ns < 8; ++ns) {
      int brow = ns * 16 + ln;
      int bbyte = brow * 128 + (((ks * 4 + g) ^ (brow & 7)) << 4);
      bf16x8 kh = *(const bf16x8*)(smem + KH_OFF + bbyte);
      bf16x8 kl = *(const bf16x8*)(smem + KL_OFF + bbyte);
      s2[ns] = __builtin_amdgcn_mfma_f32_16x16x32_bf16(qh, kh, s2[ns], 0, 0, 0);
      s2[ns] = __builtin_amdgcn_mfma_f32_16x16x32_bf16(qh, kl, s2[ns], 0, 0, 0);
      s2[ns] = __builtin_amdgcn_mfma_f32_16x16x32_bf16(ql, kh, s2[ns], 0, 0, 0);
    }
  }
  __syncthreads();

  // ---- Phase C: softmax -> prune -> mask/eb -> softmax -> P (bf16)
  const float* mk = mask + (size_t)(bn & 127) * (WT * WT);
  const float* eb = edge_bias + (size_t)h * (WT * WT);
#pragma unroll
  for (int r = 0; r < 4; ++r) {
    int m = mB + 4 * g + r;
    float sv[8];
#pragma unroll
    for (int ns = 0; ns < 8; ++ns) sv[ns] = s2[ns][r];
    float m1 = sv[0];
#pragma unroll
    for (int ns = 1; ns < 8; ++ns) m1 = fmaxf(m1, sv[ns]);
#pragma unroll
    for (int off = 1; off < 16; off <<= 1) m1 = fmaxf(m1, __shfl_xor(m1, off, 64));
    float e[8], sum1 = 0.f;
#pragma unroll
    for (int ns = 0; ns < 8; ++ns) { e[ns] = __expf(sv[ns] - m1); sum1 += e[ns]; }
#pragma unroll
    for (int off = 1; off < 16; off <<= 1) sum1 += __shfl_xor(sum1, off, 64);
    float thr = 0.5f * sum1;
    float tv[8];
#pragma unroll
    for (int ns = 0; ns < 8; ++ns) {
      int col = ns * 16 + ln;
      float mkv = mk[m * WT + col];
      float ebv = eb[m * WT + col];
      float keep = (e[ns] > thr) ? 0.f : 1.f;
      float val = sv[ns] * keep * mkv * ebv;
      tv[ns] = (val == 0.f) ? -10000.f : val;
    }
    float m2 = tv[0];
#pragma unroll
    for (int ns = 1; ns < 8; ++ns) m2 = fmaxf(m2, tv[ns]);
#pragma unroll
    for (int off = 1; off < 16; off <<= 1) m2 = fmaxf(m2, __shfl_xor(m2, off, 64));
    float e2[8], sum2 = 0.f;
#pragma unroll
    for (int ns = 0; ns < 8; ++ns) { e2[ns] = __expf(tv[ns] - m2); sum2 += e2[ns]; }
#pragma unroll
    for (int off = 1; off < 16; off <<= 1) sum2 += __shfl_xor(sum2, off, 64);
    float inv = 1.f / sum2;
#pragma unroll
    for (int ns = 0; ns < 8; ++ns)
      *(unsigned short*)(smem + P_OFF + m * 272 + (ns * 16 + ln) * 2) = bf_rne_fast(e2[ns] * inv);
  }
  __syncthreads();

  // ---- Phase D: out = P @ v  (plain bf16)
  f32x4 o4[4];
#pragma unroll
  for (int ns = 0; ns < 4; ++ns) o4[ns] = (f32x4){0.f, 0.f, 0.f, 0.f};
#pragma unroll
  for (int ks = 0; ks < 4; ++ks) {
    bf16x8 pa = *(const bf16x8*)(smem + P_OFF + (mB + ln) * 272 + ks * 64 + g * 16);
#pragma unroll
    for (int ns = 0; ns < 4; ++ns) {
      int d = ns * 16 + ln;
      bf16x8 vb = *(const bf16x8*)(smem + VT_OFF + d * 256 + (((ks * 4 + g) ^ (d & 15)) << 4));
      o4[ns] = __builtin_amdgcn_mfma_f32_16x16x32_bf16(pa, vb, o4[ns], 0, 0, 0);
    }
  }
#pragma unroll
  for (int ns = 0; ns < 4; ++ns)
#pragma unroll
    for (int r = 0; r < 4; ++r)
      out[(size_t)bn * (WT * DM) + (size_t)(mB + 4 * g + r) * DM + h * 64 + ns * 16 + ln] = o4[ns][r];
}

// ======= fused fallback (round-9 verified, 660us) ==========================
__global__ __launch_bounds__(512, 4) void attn_kernel_pre(
    const float* __restrict__ x, const unsigned char* __restrict__ wimg,
    const float* __restrict__ qkv_b, const float* __restrict__ edge_bias,
    const float* __restrict__ mask, float* __restrict__ out)
{
  __shared__ __align__(16) unsigned char smem[81920];
  const int t = threadIdx.x;
  const int lane = t & 63;
  const int w = t >> 6;
  const int g = lane >> 4;
  const int ln = lane & 15;
  const int wm = w & 3;
  const int wn = w >> 2;

  const int orig = blockIdx.x;
  const int wg = (orig & 7) * 768 + (orig >> 3);
  const int h = wg % 12;
  const int bn = wg / 12;

  const float* xw = x + (size_t)bn * (WT * DM);
  const unsigned char* whead = wimg + (size_t)h * (24 * W1CH);

  f32x4 acc[2][6];
#pragma unroll
  for (int i = 0; i < 2; ++i)
#pragma unroll
    for (int j = 0; j < 6; ++j) acc[i][j] = (f32x4){0.f, 0.f, 0.f, 0.f};

  const int exr = wm * 32 + (lane & 31);
  const int exs = wn * 2 + (lane >> 5);
  const float* xptr = xw + (size_t)exr * DM + wn * 16 + (lane >> 5) * 8;
  const int ex_w_hi = exr * 128 + ((exs ^ (exr & 7)) << 4);
  const int ex_w_lo = exr * 128 + (((exs + 4) ^ (exr & 7)) << 4);
  int ex_r_h[2], ex_r_l[2];
#pragma unroll
  for (int sm = 0; sm < 2; ++sm) {
    int rr = wm * 32 + sm * 16 + ln;
    ex_r_h[sm] = rr * 128 + ((g ^ (rr & 7)) << 4);
    ex_r_l[sm] = rr * 128 + (((g + 4) ^ (rr & 7)) << 4);
  }

  {
    gl_lds16(whead + t * 16, smem + t * 16);
    if (t < 256) gl_lds16(whead + 8192 + t * 16, smem + 8192 + t * 16);
  }
  __builtin_amdgcn_sched_barrier(0);
  float4 xa = *(const float4*)xptr;
  float4 xb = *(const float4*)(xptr + 4);
  __builtin_amdgcn_sched_barrier(0);

  for (int c = 0; c < 24; ++c) {
    float4 na, nb;
    if (c < 23) {
      na = *(const float4*)(xptr + (c + 1) * 32);
      nb = *(const float4*)(xptr + (c + 1) * 32 + 4);
    }
    __builtin_amdgcn_sched_barrier(0);
    bf16x8 xh8, xl8;
    split8(xa, xb, xh8, xl8);
    unsigned char* exb = smem + EX_OFF + (c & 1) * 16384;
    *(bf16x8*)(exb + ex_w_hi) = xh8;
    *(bf16x8*)(exb + ex_w_lo) = xl8;
    __builtin_amdgcn_sched_barrier(0);
    if (c < 23) asm volatile("s_waitcnt vmcnt(2)" ::: "memory");
    else        asm volatile("s_waitcnt vmcnt(0)" ::: "memory");
    asm volatile("s_waitcnt lgkmcnt(0)" ::: "memory");
    __builtin_amdgcn_s_barrier();
    __builtin_amdgcn_sched_barrier(0);
    if (c < 23) {
      const unsigned char* src = whead + (size_t)(c + 1) * W1CH;
      unsigned char* dst = smem + ((c + 1) & 1) * W1CH;
      gl_lds16(src + t * 16, dst + t * 16);
      if (t < 256) gl_lds16(src + 8192 + t * 16, dst + 8192 + t * 16);
    }
    __builtin_amdgcn_sched_barrier(0);
    const unsigned char* WH = smem + (c & 1) * W1CH;
    bf16x8 ah0 = *(const bf16x8*)(exb + ex_r_h[0]);
    bf16x8 al0 = *(const bf16x8*)(exb + ex_r_l[0]);
    bf16x8 ah1 = *(const bf16x8*)(exb + ex_r_h[1]);
    bf16x8 al1 = *(const bf16x8*)(exb + ex_r_l[1]);
    __builtin_amdgcn_s_setprio(1);
#pragma unroll
    for (int ns = 0; ns < 6; ++ns) {
      int j = (ns * 2 + wn) * 16 + ln;
      int sw = j * 64 + ((g ^ ((j >> 1) & 3)) << 4);
      bf16x8 bh = *(const bf16x8*)(WH + sw);
      acc[0][ns] = __builtin_amdgcn_mfma_f32_16x16x32_bf16(ah0, bh, acc[0][ns], 0, 0, 0);
      acc[1][ns] = __builtin_amdgcn_mfma_f32_16x16x32_bf16(ah1, bh, acc[1][ns], 0, 0, 0);
      if (ns < 4) {
        acc[0][ns] = __builtin_amdgcn_mfma_f32_16x16x32_bf16(al0, bh, acc[0][ns], 0, 0, 0);
        acc[1][ns] = __builtin_amdgcn_mfma_f32_16x16x32_bf16(al1, bh, acc[1][ns], 0, 0, 0);
      }
    }
    __builtin_amdgcn_s_setprio(0);
    xa = na; xb = nb;
  }
  __syncthreads();

#pragma unroll
  for (int ns = 0; ns < 6; ++ns) {
    int cc = (ns * 2 + wn) * 16 + ln;
    int sec = cc >> 6, dd = cc & 63;
    float bias = qkv_b[sec * DM + h * 64 + dd];
#pragma unroll
    for (int sm = 0; sm < 2; ++sm) {
#pragma unroll
      for (int r = 0; r < 4; ++r) {
        int m = wm * 32 + sm * 16 + 4 * g + r;
        float val = acc[sm][ns][r] + bias;
        if (cc < 64) {
          val *= 0.125f;
          unsigned short hi, lo; bf_split_fast(val, hi, lo);
          int byte = m * 128 + (((dd >> 3) ^ (m & 7)) << 4) + ((dd & 7) << 1);
          *(unsigned short*)(smem + QH_OFF + byte) = hi;
          *(unsigned short*)(smem + QL_OFF + byte) = lo;
        } else if (cc < 128) {
          unsigned short hi, lo; bf_split_fast(val, hi, lo);
          int byte = m * 128 + (((dd >> 3) ^ (m & 7)) << 4) + ((dd & 7) << 1);
          *(unsigned short*)(smem + KH_OFF + byte) = hi;
          *(unsigned short*)(smem + KL_OFF + byte) = lo;
        } else {
          int byte = dd * 256 + ((((m >> 3) ^ (dd & 15))) << 4) + ((m & 7) << 1);
          *(unsigned short*)(smem + VT_OFF + byte) = bf_rne_fast(val);
        }
      }
    }
  }
  __syncthreads();

  const int mB = w * 16;
  f32x4 s2[8];
#pragma unroll
  for (int ns = 0; ns < 8; ++ns) s2[ns] = (f32x4){0.f, 0.f, 0.f, 0.f};
#pragma unroll
  for (int ks = 0; ks < 2; ++ks) {
    int arow = mB + ln;
    int abyte = arow * 128 + (((ks * 4 + g) ^ (arow & 7)) << 4);
    bf16x8 qh = *(const bf16x8*)(smem + QH_OFF + abyte);
    bf16x8 ql = *(const bf16x8*)(smem + QL_OFF + abyte);
#pragma unroll
    for (int ns = 0; ns < 8; ++ns) {
      int brow = ns * 16 + ln;
      int bbyte = brow * 128 + (((ks * 4 + g) ^ (brow & 7)) << 4);
      bf16x8 kh = *(const bf16x8*)(smem + KH_OFF + bbyte);
      bf16x8 kl = *(const bf16x8*)(smem + KL_OFF + bbyte);
      s2[ns] = __builtin_amdgcn_mfma_f32_16x16x32_bf16(qh, kh, s2[ns], 0, 0, 0);
      s2[ns] = __builtin_amdgcn_mfma_f32_16x16x32_bf16(qh, kl, s2[ns], 0, 0, 0);
      s2[ns] = __builtin_amdgcn_mfma_f32_16x16x32_bf16(ql, kh, s2[ns], 0, 0, 0);
    }
  }
  __syncthreads();

  const float* mk = mask + (size_t)(bn & 127) * (WT * WT);
  const float* eb = edge_bias + (size_t)h * (WT * WT);
#pragma unroll
  for (int r = 0; r < 4; ++r) {
    int m = mB + 4 * g + r;
    float sv[8];
#pragma unroll
    for (int ns = 0; ns < 8; ++ns) sv[ns] = s2[ns][r];
    float m1 = sv[0];
#pragma unroll
    for (int ns = 1; ns < 8; ++ns) m1 = fmaxf(m1, sv[ns]);
#pragma unroll
    for (int off = 1; off < 16; off <<= 1) m1 = fmaxf(m1, __shfl_xor(m1, off, 64));
    float e[8], sum1 = 0.f;
#pragma unroll
    for (int ns = 0; ns < 8; ++ns) { e[ns] = __expf(sv[ns] - m1); sum1 += e[ns]; }
#pragma unroll
    for (int off = 1; off < 16; off <<= 1) sum1 += __shfl_xor(sum1, off, 64);
    float thr = 0.5f * sum1;
    float tv[8];
#pragma unroll
    for (int ns = 0; ns < 8; ++ns) {
      int col = ns * 16 + ln;
      float mkv = mk[m * WT + col];
      float ebv = eb[m * WT + col];
      float keep = (e[ns] > thr) ? 0.f : 1.f;
      float val = sv[ns] * keep * mkv * ebv;
      tv[ns] = (val == 0.f) ? -10000.f : val;
    }
    float m2 = tv[0];
#pragma unroll
    for (int ns = 1; ns < 8; ++ns) m2 = fmaxf(m2, tv[ns]);
#pragma unroll
    for (int off = 1; off < 16; off <<= 1) m2 = fmaxf(m2, __shfl_xor(m2, off, 64));
    float e2[8], sum2 = 0.f;
#pragma unroll
    for (int ns = 0; ns < 8; ++ns) { e2[ns] = __expf(tv[ns] - m2); sum2 += e2[ns]; }
#pragma unroll
    for (int off = 1; off < 16; off <<= 1) sum2 += __shfl_xor(sum2, off, 64);
    float inv = 1.f / sum2;
#pragma unroll
    for (int ns = 0; ns < 8; ++ns)
      *(unsigned short*)(smem + P_OFF + m * 272 + (ns * 16 + ln) * 2) = bf_rne_fast(e2[ns] * inv);
  }
  __syncthreads();

  f32x4 o4[4];
#pragma unroll
  for (int ns = 0; ns < 4; ++ns) o4[ns] = (f32x4){0.f, 0.f, 0.f, 0.f};
#pragma unroll
  for (int ks = 0; ks < 4; ++ks) {
    bf16x8 pa = *(const bf16x8*)(smem + P_OFF + (mB + ln) * 272 + ks * 64 + g * 16);
#pragma unroll
    for (int ns = 0; ns < 4; ++ns) {
      int d = ns * 16 + ln;
      bf16x8 vb = *(const bf16x8*)(smem + VT_OFF + d * 256 + (((ks * 4 + g) ^ (d & 15)) << 4));
      o4[ns] = __builtin_amdgcn_mfma_f32_16x16x32_bf16(pa, vb, o4[ns], 0, 0, 0);
    }
  }
#pragma unroll
  for (int ns = 0; ns < 4; ++ns)
#pragma unroll
    for (int r = 0; r < 4; ++r)
      out[(size_t)bn * (WT * DM) + (size_t)(mB + 4 * g + r) * DM + h * 64 + ns * 16 + ln] = o4[ns][r];
}

// ---------------- proj (PRE path): 64-row blocks, W 3-buf + A 3-buf --------
#define PAOFF 147456

__global__ __launch_bounds__(512) void proj_kernel_pre(
    const float* src, const unsigned char* __restrict__ wimg,
    const float* __restrict__ pb, float* dst)
{
  __shared__ __align__(16) unsigned char smem[159744];
  const int t = threadIdx.x;
  const int lane = t & 63;
  const int w = t >> 6;
  const int g = lane >> 4;
  const int ln = lane & 15;
  const int wm = w & 1;
  const int wn = w >> 1;

  const int orig = blockIdx.x;
  const int wg = (orig & 7) * 128 + (orig >> 3);
  const size_t row0 = (size_t)wg * 64;

  const int ar = t >> 3, ac4 = t & 7;
  const float* asrc = src + (row0 + ar) * DM + ac4 * 4;
  const int abyte = ar * 64 + (((ac4 >> 1) ^ ((ar >> 1) & 3)) << 4) + ((ac4 & 1) << 3);
  int afh[2];
#pragma unroll
  for (int sm = 0; sm < 2; ++sm) {
    int rr = wm * 32 + sm * 16 + ln;
    afh[sm] = rr * 64 + ((g ^ ((rr >> 1) & 3)) << 4);
  }

  {
    const unsigned char* sW = wimg + t * 16;
#pragma unroll
    for (int i = 0; i < 6; ++i) gl_lds16(sW + i * 8192, smem + t * 16 + i * 8192);
    const unsigned char* sW1 = wimg + PWCHUNK + t * 16;
#pragma unroll
    for (int i = 0; i < 6; ++i) gl_lds16(sW1 + i * 8192, smem + PWCHUNK + t * 16 + i * 8192);
  }
  __builtin_amdgcn_sched_barrier(0);
  float4 a0 = *(const float4*)asrc;
  float4 a1 = *(const float4*)(asrc + 32);
  {
    uint2 wv; wv.x = cvt_pk_bf16(a0.x, a0.y); wv.y = cvt_pk_bf16(a0.z, a0.w);
    *(uint2*)(smem + PAOFF + abyte) = wv;
  }
  __builtin_amdgcn_sched_barrier(0);

  f32x4 acc[2][12];
#pragma unroll
  for (int i = 0; i < 2; ++i)
#pragma unroll
    for (int j = 0; j < 12; ++j) acc[i][j] = (f32x4){0.f, 0.f, 0.f, 0.f};

  for (int c = 0; c < 24; ++c) {
    float4 a2;
    if (c < 22) a2 = *(const float4*)(asrc + (c + 2) * 32);
    __builtin_amdgcn_sched_barrier(0);
    if (c < 23) {
      uint2 wv; wv.x = cvt_pk_bf16(a1.x, a1.y); wv.y = cvt_pk_bf16(a1.z, a1.w);
      *(uint2*)(smem + PAOFF + ((c + 1) % 3) * 4096 + abyte) = wv;
    }
    __builtin_amdgcn_sched_barrier(0);
    if (c < 22)       asm volatile("s_waitcnt vmcnt(8)" ::: "memory");
    else if (c == 22) asm volatile("s_waitcnt vmcnt(7)" ::: "memory");
    else              asm volatile("s_waitcnt vmcnt(0)" ::: "memory");
    asm volatile("s_waitcnt lgkmcnt(0)" ::: "memory");
    __builtin_amdgcn_s_barrier();
    __builtin_amdgcn_sched_barrier(0);
    if (c < 22) {
      const unsigned char* sW = wimg + (size_t)(c + 2) * PWCHUNK + t * 16;
      unsigned char* dW = smem + ((c + 2) % 3) * PWCHUNK + t * 16;
#pragma unroll
      for (int i = 0; i < 6; ++i) gl_lds16(sW + i * 8192, dW + i * 8192);
    }
    __builtin_amdgcn_sched_barrier(0);
    const unsigned char* WB = smem + (c % 3) * PWCHUNK;
    const unsigned char* AB = smem + PAOFF + (c % 3) * 4096;
    bf16x8 af0 = *(const bf16x8*)(AB + afh[0]);
    bf16x8 af1 = *(const bf16x8*)(AB + afh[1]);
    __builtin_amdgcn_s_setprio(1);
#pragma unroll
    for (int ns = 0; ns < 12; ++ns) {
      int n = wn * 192 + ns * 16 + ln;
      bf16x8 bfrag = *(const bf16x8*)(WB + n * 64 + ((g ^ ((n >> 1) & 3)) << 4));
      acc[0][ns] = __builtin_amdgcn_mfma_f32_16x16x32_bf16(af0, bfrag, acc[0][ns], 0, 0, 0);
      acc[1][ns] = __builtin_amdgcn_mfma_f32_16x16x32_bf16(af1, bfrag, acc[1][ns], 0, 0, 0);
    }
    __builtin_amdgcn_s_setprio(0);
    a1 = a2;
  }

#pragma unroll
  for (int ns = 0; ns < 12; ++ns) {
    int col = wn * 192 + ns * 16 + ln;
    float pbv = pb[col];
#pragma unroll
    for (int sm = 0; sm < 2; ++sm)
#pragma unroll
      for (int r = 0; r < 4; ++r)
        dst[(row0 + wm * 32 + sm * 16 + 4 * g + r) * DM + col] = acc[sm][ns][r] + pbv;
  }
}

// ---------------- proj fallback (no-ws path) ------------------------------
#define PA_OFF 0
#define PW_OFF 98304

__global__ __launch_bounds__(512, 2) void proj_kernel_fb(
    const float* src, const float* __restrict__ pw,
    const float* __restrict__ pb, float* dst)
{
  __shared__ __align__(16) unsigned char smem[147456];
  const int t = threadIdx.x;
  const int lane = t & 63;
  const int w = t >> 6;
  const int g = lane >> 4;
  const int ln = lane & 15;
  const int wm = w & 1;
  const int wn = w >> 1;

  const int orig = blockIdx.x;
  const int wg = (orig & 7) * 128 + (orig >> 3);
  const size_t row0 = (size_t)wg * 64;

#pragma unroll
  for (int q = 0; q < 24; ++q) {
    int fid = q * 512 + t;
    int row = fid / 192, c4 = fid % 192;
    float4 v = *(const float4*)(src + (row0 + row) * DM + c4 * 4);
    int slot = c4 >> 1;
    int byte = row * 1536 + (((slot & ~7) | ((slot & 7) ^ (row & 7))) << 4) + ((c4 & 1) << 3);
    uint2 hv;
    hv.x = (unsigned)bf_rne(v.x) | ((unsigned)bf_rne(v.y) << 16);
    hv.y = (unsigned)bf_rne(v.z) | ((unsigned)bf_rne(v.w) << 16);
    *(uint2*)(smem + PA_OFF + byte) = hv;
  }

  f32x4 accp[2][12];
#pragma unroll
  for (int i = 0; i < 2; ++i)
#pragma unroll
    for (int j = 0; j < 12; ++j) accp[i][j] = (f32x4){0.f, 0.f, 0.f, 0.f};

  for (int c = 0; c < 24; ++c) {
    const int kc = c * 32;
    __syncthreads();
#pragma unroll
    for (int q = 0; q < 12; ++q) {
      int fid = q * 512 + t;
      int n = fid >> 3, c4 = fid & 7;
      float4 v = *(const float4*)(pw + (size_t)n * DM + kc + c4 * 4);
      int slot = (n & 1) * 4 + (c4 >> 1);
      int byte = (n >> 1) * 128 + ((slot ^ ((n >> 1) & 7)) << 4) + ((c4 & 1) << 3);
      uint2 hv;
      hv.x = (unsigned)bf_rne(v.x) | ((unsigned)bf_rne(v.y) << 16);
      hv.y = (unsigned)bf_rne(v.z) | ((unsigned)bf_rne(v.w) << 16);
      *(uint2*)(smem + PW_OFF + byte) = hv;
    }
    __syncthreads();
    bf16x8 af[2];
#pragma unroll
    for (int sm = 0; sm < 2; ++sm) {
      int row = wm * 32 + sm * 16 + ln;
      int slot = (kc >> 3) + g;
      int byte = row * 1536 + (((slot & ~7) | ((slot & 7) ^ (row & 7))) << 4);
      af[sm] = *(const bf16x8*)(smem + PA_OFF + byte);
    }
#pragma unroll
    for (int j = 0; j < 12; ++j) {
      int n = (wn * 12 + j) * 16 + ln;
      int slot = (n & 1) * 4 + g;
      bf16x8 bf_ = *(const bf16x8*)(smem + PW_OFF + (n >> 1) * 128 + ((slot ^ ((n >> 1) & 7)) << 4));
#pragma unroll
      for (int sm = 0; sm < 2; ++sm)
        accp[sm][j] = __builtin_amdgcn_mfma_f32_16x16x32_bf16(af[sm], bf_, accp[sm][j], 0, 0, 0);
    }
  }

#pragma unroll
  for (int j = 0; j < 12; ++j) {
    int col = (wn * 12 + j) * 16 + ln;
    float pbv = pb[col];
#pragma unroll
    for (int sm = 0; sm < 2; ++sm)
#pragma unroll
      for (int r = 0; r < 4; ++r)
        dst[(row0 + wm * 32 + sm * 16 + 4 * g + r) * DM + col] = accp[sm][j][r] + pbv;
  }
}

// ---------------- attn fallback (no-ws path, round-2 verified) -------------
__global__ __launch_bounds__(512, 2) void attn_kernel_fb(
    const float* __restrict__ x, const float* __restrict__ qkv_w,
    const float* __restrict__ qkv_b, const float* __restrict__ edge_bias,
    const float* __restrict__ mask, float* __restrict__ out)
{
  __shared__ __align__(16) unsigned char smem[98304];
  const int t = threadIdx.x;
  const int lane = t & 63;
  const int w = t >> 6;
  const int g = lane >> 4;
  const int ln = lane & 15;
  const int wm = w & 3;
  const int wn = w >> 2;

  const int orig = blockIdx.x;
  const int wg = (orig & 7) * 768 + (orig >> 3);
  const int h = wg % 12;
  const int bn = wg / 12;

  const float* xw = x + (size_t)bn * (WT * DM);

  f32x4 acc[2][6];
#pragma unroll
  for (int i = 0; i < 2; ++i)
#pragma unroll
    for (int j = 0; j < 6; ++j) acc[i][j] = (f32x4){0.f, 0.f, 0.f, 0.f};

  float4 wreg[6], xreg[8];
#pragma unroll
  for (int q = 0; q < 6; ++q) {
    int fid = q * 512 + t;
    int j = fid >> 4, c4 = fid & 15;
    int sec = j >> 6, d = j & 63;
    wreg[q] = *(const float4*)(qkv_w + (size_t)(sec * DM + h * 64 + d) * DM + c4 * 4);
  }

  for (int c = 0; c < 12; ++c) {
    const int kc = c * 64;
#pragma unroll
    for (int sm = 0; sm < 2; ++sm)
#pragma unroll
      for (int ks = 0; ks < 2; ++ks) {
        int row = wm * 32 + sm * 16 + ln;
        const float* p = xw + (size_t)row * DM + kc + ks * 32 + g * 8;
        xreg[(sm * 2 + ks) * 2 + 0] = *(const float4*)p;
        xreg[(sm * 2 + ks) * 2 + 1] = *(const float4*)(p + 4);
      }
    unsigned char* WH = smem + (c & 1) * 49152;
    unsigned char* WL = WH + 24576;
#pragma unroll
    for (int q = 0; q < 6; ++q) {
      int fid = q * 512 + t;
      int j = fid >> 4, c4 = fid & 15;
      int byte = j * 128 + ((((c4 >> 1) ^ (j & 7))) << 4) + ((c4 & 1) << 3);
      float4 v = wreg[q];
      unsigned short h0, h1, h2, h3, l0, l1, l2, l3;
      bf_split(v.x, h0, l0); bf_split(v.y, h1, l1);
      bf_split(v.z, h2, l2); bf_split(v.w, h3, l3);
      uint2 hv, lv;
      hv.x = (unsigned)h0 | ((unsigned)h1 << 16); hv.y = (unsigned)h2 | ((unsigned)h3 << 16);
      lv.x = (unsigned)l0 | ((unsigned)l1 << 16); lv.y = (unsigned)l2 | ((unsigned)l3 << 16);
      *(uint2*)(WH + byte) = hv;
      *(uint2*)(WL + byte) = lv;
    }
    if (c < 11) {
#pragma unroll
      for (int q = 0; q < 6; ++q) {
        int fid = q * 512 + t;
        int j = fid >> 4, c4 = fid & 15;
        int sec = j >> 6, d = j & 63;
        wreg[q] = *(const float4*)(qkv_w + (size_t)(sec * DM + h * 64 + d) * DM + kc + 64 + c4 * 4);
      }
    }
    __syncthreads();
#pragma unroll
    for (int ks = 0; ks < 2; ++ks) {
      bf16x8 ah[2], al[2];
#pragma unroll
      for (int sm = 0; sm < 2; ++sm)
        split8(xreg[(sm * 2 + ks) * 2 + 0], xreg[(sm * 2 + ks) * 2 + 1], ah[sm], al[sm]);
#pragma unroll
      for (int ns = 0; ns < 6; ++ns) {
        int j = wn * 96 + ns * 16 + ln;
        int sw = j * 128 + (((ks * 4 + g) ^ (j & 7)) << 4);
        bf16x8 bh = *(const bf16x8*)(WH + sw);
        bf16x8 bl = *(const bf16x8*)(WL + sw);
#pragma unroll
        for (int sm = 0; sm < 2; ++sm) {
          acc[sm][ns] = __builtin_amdgcn_mfma_f32_16x16x32_bf16(ah[sm], bh, acc[sm][ns], 0, 0, 0);
          acc[sm][ns] = __builtin_amdgcn_mfma_f32_16x16x32_bf16(ah[sm], bl, acc[sm][ns], 0, 0, 0);
          acc[sm][ns] = __builtin_amdgcn_mfma_f32_16x16x32_bf16(al[sm], bh, acc[sm][ns], 0, 0, 0);
        }
      }
    }
  }
  __syncthreads();

#pragma unroll
  for (int sm = 0; sm < 2; ++sm)
#pragma unroll
    for (int ns = 0; ns < 6; ++ns) {
      int cc = wn * 96 + ns * 16 + ln;
      int sec = cc >> 6, dd = cc & 63;
      float bias = qkv_b[sec * DM + h * 64 + dd];
#pragma unroll
      for (int r = 0; r < 4; ++r) {
        int m = wm * 32 + sm * 16 + 4 * g + r;
        float val = acc[sm][ns][r] + bias;
        if (cc < 64) {
          val *= 0.125f;
          unsigned short hi, lo; bf_split(val, hi, lo);
          int byte = m * 128 + ((((dd >> 3) ^ (m & 7))) << 4) + ((dd & 7) << 1);
          *(unsigned short*)(smem + QH_OFF + byte) = hi;
          *(unsigned short*)(smem + QL_OFF + byte) = lo;
        } else if (cc < 128) {
          unsigned short hi, lo; bf_split(val, hi, lo);
          int byte = m * 128 + ((((dd >> 3) ^ (m & 7))) << 4) + ((dd & 7) << 1);
          *(unsigned short*)(smem + KH_OFF + byte) = hi;
          *(unsigned short*)(smem + KL_OFF + byte) = lo;
        } else {
          *(unsigned short*)(smem + VT_OFF + dd * 272 + m * 2) = bf_rne(val);
        }
      }
    }
  __syncthreads();

  const int mB = w * 16;
  f32x4 s2[8];
#pragma unroll
  for (int ns = 0; ns < 8; ++ns) s2[ns] = (f32x4){0.f, 0.f, 0.f, 0.f};
#pragma unroll
  for (int ks = 0; ks < 2; ++ks) {
    int arow = mB + ln;
    int abyte = arow * 128 + (((ks * 4 + g) ^ (arow & 7)) << 4);
    bf16x8 qh = *(const bf16x8*)(smem + QH_OFF + abyte);
    bf16x8 ql = *(const bf16x8*)(smem + QL_OFF + abyte);
#pragma unroll
    for (int ns = 0; ns < 8; ++ns) {
      int brow = ns * 16 + ln;
      int bbyte = brow * 128 + (((ks * 4 + g) ^ (brow & 7)) << 4);
      bf16x8 kh = *(const bf16x8*)(smem + KH_OFF + bbyte);
      bf16x8 kl = *(const bf16x8*)(smem + KL_OFF + bbyte);
      s2[ns] = __builtin_amdgcn_mfma_f32_16x16x32_bf16(qh, kh, s2[ns], 0, 0, 0);
      s2[ns] = __builtin_amdgcn_mfma_f32_16x16x32_bf16(qh, kl, s2[ns], 0, 0, 0);
      s2[ns] = __builtin_amdgcn_mfma_f32_16x16x32_bf16(ql, kh, s2[ns], 0, 0, 0);
    }
  }
  __syncthreads();

  const float* mk = mask + (size_t)(bn & 127) * (WT * WT);
  const float* eb = edge_bias + (size_t)h * (WT * WT);
#pragma unroll
  for (int r = 0; r < 4; ++r) {
    int m = mB + 4 * g + r;
    float sv[8];
#pragma unroll
    for (int ns = 0; ns < 8; ++ns) sv[ns] = s2[ns][r];
    float m1 = sv[0];
#pragma unroll
    for (int ns = 1; ns < 8; ++ns) m1 = fmaxf(m1, sv[ns]);
#pragma unroll
    for (int off = 1; off < 16; off <<= 1) m1 = fmaxf(m1, __shfl_xor(m1, off, 64));
    float e[8], sum1 = 0.f;
#pragma unroll
    for (int ns = 0; ns < 8; ++ns) { e[ns] = __expf(sv[ns] - m1); sum1 += e[ns]; }
#pragma unroll
    for (int off = 1; off < 16; off <<= 1) sum1 += __shfl_xor(sum1, off, 64);
    float thr = 0.5f * sum1;
    float tv[8];
#pragma unroll
    for (int ns = 0; ns < 8; ++ns) {
      int col = ns * 16 + ln;
      float mkv = mk[m * WT + col];
      float ebv = eb[m * WT + col];
      float keep = (e[ns] > thr) ? 0.f : 1.f;
      float val = sv[ns] * keep * mkv * ebv;
      tv[ns] = (val == 0.f) ? -10000.f : val;
    }
    float m2 = tv[0];
#pragma unroll
    for (int ns = 1; ns < 8; ++ns) m2 = fmaxf(m2, tv[ns]);
#pragma unroll
    for (int off = 1; off < 16; off <<= 1) m2 = fmaxf(m2, __shfl_xor(m2, off, 64));
    float e2[8], sum2 = 0.f;
#pragma unroll
    for (int ns = 0; ns < 8; ++ns) { e2[ns] = __expf(tv[ns] - m2); sum2 += e2[ns]; }
#pragma unroll
    for (int off = 1; off < 16; off <<= 1) sum2 += __shfl_xor(sum2, off, 64);
    float inv = 1.f / sum2;
#pragma unroll
    for (int ns = 0; ns < 8; ++ns)
      *(unsigned short*)(smem + P_OFF + m * 272 + (ns * 16 + ln) * 2) = bf_rne(e2[ns] * inv);
  }
  __syncthreads();

  f32x4 o4[4];
#pragma unroll
  for (int ns = 0; ns < 4; ++ns) o4[ns] = (f32x4){0.f, 0.f, 0.f, 0.f};
#pragma unroll
  for (int ks = 0; ks < 4; ++ks) {
    bf16x8 pa = *(const bf16x8*)(smem + P_OFF + (mB + ln) * 272 + ks * 64 + g * 16);
#pragma unroll
    for (int ns = 0; ns < 4; ++ns) {
      bf16x8 vb = *(const bf16x8*)(smem + VT_OFF + (ns * 16 + ln) * 272 + ks * 64 + g * 16);
      o4[ns] = __builtin_amdgcn_mfma_f32_16x16x32_bf16(pa, vb, o4[ns], 0, 0, 0);
    }
  }
#pragma unroll
  for (int ns = 0; ns < 4; ++ns)
#pragma unroll
    for (int r = 0; r < 4; ++r)
      out[(size_t)bn * (WT * DM) + (size_t)(mB + 4 * g + r) * DM + h * 64 + ns * 16 + ln] = o4[ns][r];
}

extern "C" void kernel_launch(void* const* d_in, const int* in_sizes, int n_in,
                              void* d_out, int out_size, void* d_ws, size_t ws_size,
                              hipStream_t stream) {
  const float* x         = (const float*)d_in[0];
  const float* qkv_w     = (const float*)d_in[1];
  const float* qkv_b     = (const float*)d_in[2];
  const float* proj_w    = (const float*)d_in[3];
  const float* proj_b    = (const float*)d_in[4];
  const float* edge_bias = (const float*)d_in[5];
  const float* mask      = (const float*)d_in[6];
  float* out = (float*)d_out;

  const bool p1 = (d_ws != nullptr) && (ws_size >= WS_W1);
  const bool p2 = (d_ws != nullptr) && (ws_size >= WS_W1 + WS_W2);
  unsigned char* wsW = (unsigned char*)d_ws;
  unsigned char* wsP = wsW + WS_W1;
  unsigned char* wsA = wsP + WS_W2;

  // split-path batch count: nb=2 (252MB, ~L3-resident, big grids) preferred
  const size_t base = WS_W1 + WS_W2;
  int nb = 0;
  if (p2 && ws_size >= base + (size_t)256 * 12 * IMG_SZ)      nb = 2;
  else if (p2 && ws_size >= base + (size_t)128 * 12 * IMG_SZ) nb = 4;

  if (p1) split_w_kernel<<<1728, 256, 0, stream>>>(qkv_w, wsW);
  if (p2) split_pw_kernel<<<576, 256, 0, stream>>>(proj_w, wsP);

  if (nb) {
    const int pb = 256 / nb;   // window-pairs per batch
    for (int b = 0; b < nb; ++b) {
      qkv2_kernel<<<pb * 12, 512, 0, stream>>>(x, wsW, qkv_b, wsA, b * pb);
      attn2_kernel<<<pb * 24, 512, 0, stream>>>(wsA, edge_bias, mask, out, b * pb * 2);
    }
  } else if (p1) {
    attn_kernel_pre<<<NW * NH, 512, 0, stream>>>(x, wsW, qkv_b, edge_bias, mask, out);
  } else {
    attn_kernel_fb<<<NW * NH, 512, 0, stream>>>(x, qkv_w, qkv_b, edge_bias, mask, out);
  }

  if (p2) {
    proj_kernel_pre<<<1024, 512, 0, stream>>>(out, wsP, proj_b, out);
  } else {
    proj_kernel_fb<<<1024, 512, 0, stream>>>(out, proj_w, proj_b, out);
  }
}

// Round 12
// 702.769 us; speedup vs baseline: 1.2815x; 1.2681x over previous
//
#include <hip/hip_runtime.h>

#define NW 512
#define WT 128
#define DM 768
#define NH 12

typedef __attribute__((ext_vector_type(8))) short bf16x8;
typedef __attribute__((ext_vector_type(4))) float f32x4;
typedef __attribute__((ext_vector_type(4))) unsigned int u32x4;

#define W1CH 12288                            // one (head,chunk) attn W image (single bf16)
#define WS_W1 ((size_t)NH * 24 * W1CH)        // 3,538,944 attn W images
#define PWCHUNK 49152                         // one proj W k32 chunk image
#define WS_W2 ((size_t)24 * PWCHUNK)          // 1,179,648 proj W image

__device__ __forceinline__ unsigned short bf_rne(float v) {
  unsigned u = __float_as_uint(v);
  unsigned r = u + 0x7fffu + ((u >> 16) & 1u);
  return (unsigned short)(r >> 16);
}
__device__ __forceinline__ void bf_split(float v, unsigned short& hi, unsigned short& lo) {
  hi = bf_rne(v);
  float hf = __uint_as_float(((unsigned)hi) << 16);
  lo = bf_rne(v - hf);
}

__device__ __forceinline__ unsigned cvt_pk_bf16(float a, float b) {
  unsigned r;
  asm("v_cvt_pk_bf16_f32 %0, %1, %2" : "=v"(r) : "v"(a), "v"(b));
  return r;
}
__device__ __forceinline__ unsigned short bf_rne_fast(float v) {
  return (unsigned short)cvt_pk_bf16(v, v);
}
__device__ __forceinline__ void bf_split_fast(float v, unsigned short& hi, unsigned short& lo) {
  unsigned hp = cvt_pk_bf16(v, v);
  float hf = __uint_as_float(hp << 16);
  lo = (unsigned short)cvt_pk_bf16(v - hf, v - hf);
  hi = (unsigned short)hp;
}

__device__ __forceinline__ void split8(float4 v0, float4 v1, bf16x8& hi, bf16x8& lo) {
  float f[8] = {v0.x, v0.y, v0.z, v0.w, v1.x, v1.y, v1.z, v1.w};
  u32x4 hu, lu;
#pragma unroll
  for (int i = 0; i < 4; ++i) {
    float e0 = f[2 * i], e1 = f[2 * i + 1];
    unsigned hp = cvt_pk_bf16(e0, e1);
    float h0 = __uint_as_float(hp << 16);
    float h1 = __uint_as_float(hp & 0xffff0000u);
    lu[i] = cvt_pk_bf16(e0 - h0, e1 - h1);
    hu[i] = hp;
  }
  hi = __builtin_bit_cast(bf16x8, hu);
  lo = __builtin_bit_cast(bf16x8, lu);
}

__device__ __forceinline__ void gl_lds16(const void* g, void* l) {
  __builtin_amdgcn_global_load_lds(
      (const __attribute__((address_space(1))) void*)g,
      (__attribute__((address_space(3))) void*)l, 16, 0, 0);
}

// ---------------- precompute: attn W -> single-bf16 swizzled LDS images ----
__global__ __launch_bounds__(256) void split_w_kernel(
    const float* __restrict__ qkv_w, unsigned char* __restrict__ wsW)
{
  int id = blockIdx.x * 256 + threadIdx.x;
  int c4 = id & 7;
  int j  = (id >> 3) % 192;
  int hc = (id >> 3) / 192;
  int c  = hc % 24;
  int h  = hc / 24;
  int sec = j >> 6, d = j & 63;
  const float* src = qkv_w + (size_t)(sec * DM + h * 64 + d) * DM + c * 32 + c4 * 4;
  float4 v = *(const float4*)src;
  uint2 hv;
  hv.x = (unsigned)bf_rne(v.x) | ((unsigned)bf_rne(v.y) << 16);
  hv.y = (unsigned)bf_rne(v.z) | ((unsigned)bf_rne(v.w) << 16);
  int byte = j * 64 + (((c4 >> 1) ^ ((j >> 1) & 3)) << 4) + ((c4 & 1) << 3);
  *(uint2*)(wsW + (size_t)hc * W1CH + byte) = hv;
}

// ---------------- precompute: proj W -> bf16 swizzled LDS image ------------
__global__ __launch_bounds__(256) void split_pw_kernel(
    const float* __restrict__ pw, unsigned char* __restrict__ wsP)
{
  int id = blockIdx.x * 256 + threadIdx.x;
  int c4 = id & 7;
  int n  = (id >> 3) % 768;
  int c  = (id >> 3) / 768;
  float4 v = *(const float4*)(pw + (size_t)n * DM + c * 32 + c4 * 4);
  uint2 hv;
  hv.x = (unsigned)bf_rne(v.x) | ((unsigned)bf_rne(v.y) << 16);
  hv.y = (unsigned)bf_rne(v.z) | ((unsigned)bf_rne(v.w) << 16);
  int byte = n * 64 + (((c4 >> 1) ^ ((n >> 1) & 3)) << 4) + ((c4 & 1) << 3);
  *(uint2*)(wsP + (size_t)c * PWCHUNK + byte) = hv;
}

// ---------------- attn (PRE path) LDS layout (bytes) ----------------
// Phase A: W dbuf 2 x 12288 @0 ; EX dbuf 2 x 16384 @49152  (81920 total)
// Post-A : QH@0 QL@16384 KH@32768 KL@49152 (each [128]x128B swz)
//          VT@65536: [64 d]x256B ;  P@0: [128]x272B bf16 overlay
#define QH_OFF 0
#define QL_OFF 16384
#define KH_OFF 32768
#define KL_OFF 49152
#define VT_OFF 65536
#define EX_OFF 49152
#define P_OFF  0

__global__ __launch_bounds__(512, 4) void attn_kernel_pre(
    const float* __restrict__ x, const unsigned char* __restrict__ wimg,
    const float* __restrict__ qkv_b, const float* __restrict__ edge_bias,
    const float* __restrict__ mask, float* __restrict__ out)
{
  __shared__ __align__(16) unsigned char smem[81920];
  const int t = threadIdx.x;
  const int lane = t & 63;
  const int w = t >> 6;
  const int g = lane >> 4;
  const int ln = lane & 15;
  const int wm = w & 3;
  const int wn = w >> 2;

  const int orig = blockIdx.x;
  const int wg = (orig & 7) * 768 + (orig >> 3);
  const int h = wg % 12;
  const int bn = wg / 12;

  const float* xw = x + (size_t)bn * (WT * DM);
  const unsigned char* whead = wimg + (size_t)h * (24 * W1CH);

  f32x4 acc[2][6];
#pragma unroll
  for (int i = 0; i < 2; ++i)
#pragma unroll
    for (int j = 0; j < 6; ++j) acc[i][j] = (f32x4){0.f, 0.f, 0.f, 0.f};

  // x half-load: this wave stages rows wm*32+(lane&31), k-half wn*16+(lane>>5)*8
  const int exr = wm * 32 + (lane & 31);
  const int exs = wn * 2 + (lane >> 5);
  const float* xptr = xw + (size_t)exr * DM + wn * 16 + (lane >> 5) * 8;
  const int ex_w_hi = exr * 128 + ((exs ^ (exr & 7)) << 4);
  const int ex_w_lo = exr * 128 + (((exs + 4) ^ (exr & 7)) << 4);
  int ex_r_h[2], ex_r_l[2];
#pragma unroll
  for (int sm = 0; sm < 2; ++sm) {
    int rr = wm * 32 + sm * 16 + ln;
    ex_r_h[sm] = rr * 128 + ((g ^ (rr & 7)) << 4);
    ex_r_l[sm] = rr * 128 + (((g + 4) ^ (rr & 7)) << 4);
  }

  // prologue: stage W(0) into buf0 (12288 B: all threads + waves 0-3), then x(0)
  {
    gl_lds16(whead + t * 16, smem + t * 16);
    if (t < 256) gl_lds16(whead + 8192 + t * 16, smem + 8192 + t * 16);
  }
  __builtin_amdgcn_sched_barrier(0);
  float4 xa = *(const float4*)xptr;
  float4 xb = *(const float4*)(xptr + 4);
  __builtin_amdgcn_sched_barrier(0);

  for (int c = 0; c < 24; ++c) {
    // (a) issue x(c+1) loads
    float4 na, nb;
    if (c < 23) {
      na = *(const float4*)(xptr + (c + 1) * 32);
      nb = *(const float4*)(xptr + (c + 1) * 32 + 4);
    }
    __builtin_amdgcn_sched_barrier(0);
    // (b) split x(c) (compiler waits x(c)) + exchange writes
    bf16x8 xh8, xl8;
    split8(xa, xb, xh8, xl8);
    unsigned char* exb = smem + EX_OFF + (c & 1) * 16384;
    *(bf16x8*)(exb + ex_w_hi) = xh8;
    *(bf16x8*)(exb + ex_w_lo) = xl8;
    __builtin_amdgcn_sched_barrier(0);
    // (c) retire own W(c) DMA (keep x(c+1) in flight), drain LDS writes, barrier
    if (c < 23) asm volatile("s_waitcnt vmcnt(2)" ::: "memory");
    else        asm volatile("s_waitcnt vmcnt(0)" ::: "memory");
    asm volatile("s_waitcnt lgkmcnt(0)" ::: "memory");
    __builtin_amdgcn_s_barrier();
    __builtin_amdgcn_sched_barrier(0);
    // (d) stage W(c+1) into other buffer
    if (c < 23) {
      const unsigned char* src = whead + (size_t)(c + 1) * W1CH;
      unsigned char* dst = smem + ((c + 1) & 1) * W1CH;
      gl_lds16(src + t * 16, dst + t * 16);
      if (t < 256) gl_lds16(src + 8192 + t * 16, dst + 8192 + t * 16);
    }
    __builtin_amdgcn_sched_barrier(0);
    // (e) fragments + MFMA (2-pass q/k, 1-pass v)
    const unsigned char* WH = smem + (c & 1) * W1CH;
    bf16x8 ah0 = *(const bf16x8*)(exb + ex_r_h[0]);
    bf16x8 al0 = *(const bf16x8*)(exb + ex_r_l[0]);
    bf16x8 ah1 = *(const bf16x8*)(exb + ex_r_h[1]);
    bf16x8 al1 = *(const bf16x8*)(exb + ex_r_l[1]);
    __builtin_amdgcn_s_setprio(1);
    // strips: cc = (ns*2+wn)*16+ln ; ns<4 -> q/k (2-pass), ns>=4 -> v (1-pass)
#pragma unroll
    for (int ns = 0; ns < 6; ++ns) {
      int j = (ns * 2 + wn) * 16 + ln;
      int sw = j * 64 + ((g ^ ((j >> 1) & 3)) << 4);
      bf16x8 bh = *(const bf16x8*)(WH + sw);
      acc[0][ns] = __builtin_amdgcn_mfma_f32_16x16x32_bf16(ah0, bh, acc[0][ns], 0, 0, 0);
      acc[1][ns] = __builtin_amdgcn_mfma_f32_16x16x32_bf16(ah1, bh, acc[1][ns], 0, 0, 0);
      if (ns < 4) {
        acc[0][ns] = __builtin_amdgcn_mfma_f32_16x16x32_bf16(al0, bh, acc[0][ns], 0, 0, 0);
        acc[1][ns] = __builtin_amdgcn_mfma_f32_16x16x32_bf16(al1, bh, acc[1][ns], 0, 0, 0);
      }
    }
    __builtin_amdgcn_s_setprio(0);
    xa = na; xb = nb;
  }
  __syncthreads();   // full drain before overlaying W/EX buffers

  // ---- epilogue: bias, scatter q(split,scaled)/k(split)/v(VT bf16)
#pragma unroll
  for (int ns = 0; ns < 6; ++ns) {
    int cc = (ns * 2 + wn) * 16 + ln;
    int sec = cc >> 6, dd = cc & 63;
    float bias = qkv_b[sec * DM + h * 64 + dd];
#pragma unroll
    for (int sm = 0; sm < 2; ++sm) {
#pragma unroll
      for (int r = 0; r < 4; ++r) {
        int m = wm * 32 + sm * 16 + 4 * g + r;
        float val = acc[sm][ns][r] + bias;
        if (cc < 64) {
          val *= 0.125f;
          unsigned short hi, lo; bf_split_fast(val, hi, lo);
          int byte = m * 128 + (((dd >> 3) ^ (m & 7)) << 4) + ((dd & 7) << 1);
          *(unsigned short*)(smem + QH_OFF + byte) = hi;
          *(unsigned short*)(smem + QL_OFF + byte) = lo;
        } else if (cc < 128) {
          unsigned short hi, lo; bf_split_fast(val, hi, lo);
          int byte = m * 128 + (((dd >> 3) ^ (m & 7)) << 4) + ((dd & 7) << 1);
          *(unsigned short*)(smem + KH_OFF + byte) = hi;
          *(unsigned short*)(smem + KL_OFF + byte) = lo;
        } else {
          int byte = dd * 256 + ((((m >> 3) ^ (dd & 15))) << 4) + ((m & 7) << 1);
          *(unsigned short*)(smem + VT_OFF + byte) = bf_rne_fast(val);
        }
      }
    }
  }
  __syncthreads();

  // ---- Phase B: S = q @ k^T (split 3-pass), wave w owns rows w*16..+16
  const int mB = w * 16;
  f32x4 s2[8];
#pragma unroll
  for (int ns = 0; ns < 8; ++ns) s2[ns] = (f32x4){0.f, 0.f, 0.f, 0.f};
#pragma unroll
  for (int ks = 0; ks < 2; ++ks) {
    int arow = mB + ln;
    int abyte = arow * 128 + (((ks * 4 + g) ^ (arow & 7)) << 4);
    bf16x8 qh = *(const bf16x8*)(smem + QH_OFF + abyte);
    bf16x8 ql = *(const bf16x8*)(smem + QL_OFF + abyte);
#pragma unroll
    for (int ns = 0; ns < 8; ++ns) {
      int brow = ns * 16 + ln;
      int bbyte = brow * 128 + (((ks * 4 + g) ^ (brow & 7)) << 4);
      bf16x8 kh = *(const bf16x8*)(smem + KH_OFF + bbyte);
      bf16x8 kl = *(const bf16x8*)(smem + KL_OFF + bbyte);
      s2[ns] = __builtin_amdgcn_mfma_f32_16x16x32_bf16(qh, kh, s2[ns], 0, 0, 0);
      s2[ns] = __builtin_amdgcn_mfma_f32_16x16x32_bf16(qh, kl, s2[ns], 0, 0, 0);
      s2[ns] = __builtin_amdgcn_mfma_f32_16x16x32_bf16(ql, kh, s2[ns], 0, 0, 0);
    }
  }
  __syncthreads();   // q/k dead; P may overlay

  // ---- Phase C: softmax -> prune -> mask/eb -> softmax -> P (bf16)
  const float* mk = mask + (size_t)(bn & 127) * (WT * WT);
  const float* eb = edge_bias + (size_t)h * (WT * WT);
#pragma unroll
  for (int r = 0; r < 4; ++r) {
    int m = mB + 4 * g + r;
    float sv[8];
#pragma unroll
    for (int ns = 0; ns < 8; ++ns) sv[ns] = s2[ns][r];
    float m1 = sv[0];
#pragma unroll
    for (int ns = 1; ns < 8; ++ns) m1 = fmaxf(m1, sv[ns]);
#pragma unroll
    for (int off = 1; off < 16; off <<= 1) m1 = fmaxf(m1, __shfl_xor(m1, off, 64));
    float e[8], sum1 = 0.f;
#pragma unroll
    for (int ns = 0; ns < 8; ++ns) { e[ns] = __expf(sv[ns] - m1); sum1 += e[ns]; }
#pragma unroll
    for (int off = 1; off < 16; off <<= 1) sum1 += __shfl_xor(sum1, off, 64);
    float thr = 0.5f * sum1;
    float tv[8];
#pragma unroll
    for (int ns = 0; ns < 8; ++ns) {
      int col = ns * 16 + ln;
      float mkv = mk[m * WT + col];
      float ebv = eb[m * WT + col];
      float keep = (e[ns] > thr) ? 0.f : 1.f;
      float val = sv[ns] * keep * mkv * ebv;
      tv[ns] = (val == 0.f) ? -10000.f : val;
    }
    float m2 = tv[0];
#pragma unroll
    for (int ns = 1; ns < 8; ++ns) m2 = fmaxf(m2, tv[ns]);
#pragma unroll
    for (int off = 1; off < 16; off <<= 1) m2 = fmaxf(m2, __shfl_xor(m2, off, 64));
    float e2[8], sum2 = 0.f;
#pragma unroll
    for (int ns = 0; ns < 8; ++ns) { e2[ns] = __expf(tv[ns] - m2); sum2 += e2[ns]; }
#pragma unroll
    for (int off = 1; off < 16; off <<= 1) sum2 += __shfl_xor(sum2, off, 64);
    float inv = 1.f / sum2;
#pragma unroll
    for (int ns = 0; ns < 8; ++ns)
      *(unsigned short*)(smem + P_OFF + m * 272 + (ns * 16 + ln) * 2) = bf_rne_fast(e2[ns] * inv);
  }
  __syncthreads();

  // ---- Phase D: out = P @ v  (plain bf16)
  f32x4 o4[4];
#pragma unroll
  for (int ns = 0; ns < 4; ++ns) o4[ns] = (f32x4){0.f, 0.f, 0.f, 0.f};
#pragma unroll
  for (int ks = 0; ks < 4; ++ks) {
    bf16x8 pa = *(const bf16x8*)(smem + P_OFF + (mB + ln) * 272 + ks * 64 + g * 16);
#pragma unroll
    for (int ns = 0; ns < 4; ++ns) {
      int d = ns * 16 + ln;
      bf16x8 vb = *(const bf16x8*)(smem + VT_OFF + d * 256 + (((ks * 4 + g) ^ (d & 15)) << 4));
      o4[ns] = __builtin_amdgcn_mfma_f32_16x16x32_bf16(pa, vb, o4[ns], 0, 0, 0);
    }
  }
#pragma unroll
  for (int ns = 0; ns < 4; ++ns)
#pragma unroll
    for (int r = 0; r < 4; ++r)
      out[(size_t)bn * (WT * DM) + (size_t)(mB + 4 * g + r) * DM + h * 64 + ns * 16 + ln] = o4[ns][r];
}

// ---------------- proj (PRE path): 64-row blocks, W 3-buf + A 3-buf --------
// LDS: W 3 x 49152 @0 ; A 3 x 4096 @147456   (159744 total)
#define PAOFF 147456

__global__ __launch_bounds__(512) void proj_kernel_pre(
    const float* src, const unsigned char* __restrict__ wimg,
    const float* __restrict__ pb, float* dst)
{
  __shared__ __align__(16) unsigned char smem[159744];
  const int t = threadIdx.x;
  const int lane = t & 63;
  const int w = t >> 6;
  const int g = lane >> 4;
  const int ln = lane & 15;
  const int wm = w & 1;
  const int wn = w >> 1;

  const int orig = blockIdx.x;
  const int wg = (orig & 7) * 128 + (orig >> 3);
  const size_t row0 = (size_t)wg * 64;

  const int ar = t >> 3, ac4 = t & 7;
  const float* asrc = src + (row0 + ar) * DM + ac4 * 4;
  const int abyte = ar * 64 + (((ac4 >> 1) ^ ((ar >> 1) & 3)) << 4) + ((ac4 & 1) << 3);
  int afh[2];
#pragma unroll
  for (int sm = 0; sm < 2; ++sm) {
    int rr = wm * 32 + sm * 16 + ln;
    afh[sm] = rr * 64 + ((g ^ ((rr >> 1) & 3)) << 4);
  }

  // prologue: stage W(0),W(1); load A(0),A(1); write A(0)->Abuf0
  {
    const unsigned char* sW = wimg + t * 16;
#pragma unroll
    for (int i = 0; i < 6; ++i) gl_lds16(sW + i * 8192, smem + t * 16 + i * 8192);
    const unsigned char* sW1 = wimg + PWCHUNK + t * 16;
#pragma unroll
    for (int i = 0; i < 6; ++i) gl_lds16(sW1 + i * 8192, smem + PWCHUNK + t * 16 + i * 8192);
  }
  __builtin_amdgcn_sched_barrier(0);
  float4 a0 = *(const float4*)asrc;
  float4 a1 = *(const float4*)(asrc + 32);
  {
    uint2 wv; wv.x = cvt_pk_bf16(a0.x, a0.y); wv.y = cvt_pk_bf16(a0.z, a0.w);
    *(uint2*)(smem + PAOFF + abyte) = wv;
  }
  __builtin_amdgcn_sched_barrier(0);

  f32x4 acc[2][12];
#pragma unroll
  for (int i = 0; i < 2; ++i)
#pragma unroll
    for (int j = 0; j < 12; ++j) acc[i][j] = (f32x4){0.f, 0.f, 0.f, 0.f};

  for (int c = 0; c < 24; ++c) {
    // (a) issue A(c+2)
    float4 a2;
    if (c < 22) a2 = *(const float4*)(asrc + (c + 2) * 32);
    __builtin_amdgcn_sched_barrier(0);
    // (b) cvt + write A(c+1) into Abuf (c+1)%3
    if (c < 23) {
      uint2 wv; wv.x = cvt_pk_bf16(a1.x, a1.y); wv.y = cvt_pk_bf16(a1.z, a1.w);
      *(uint2*)(smem + PAOFF + ((c + 1) % 3) * 4096 + abyte) = wv;
    }
    __builtin_amdgcn_sched_barrier(0);
    // (c) retire own W(c) DMA, drain LDS writes, barrier
    if (c < 22)       asm volatile("s_waitcnt vmcnt(8)" ::: "memory");
    else if (c == 22) asm volatile("s_waitcnt vmcnt(7)" ::: "memory");
    else              asm volatile("s_waitcnt vmcnt(0)" ::: "memory");
    asm volatile("s_waitcnt lgkmcnt(0)" ::: "memory");
    __builtin_amdgcn_s_barrier();
    __builtin_amdgcn_sched_barrier(0);
    // (d) stage W(c+2) into Wbuf (c+2)%3
    if (c < 22) {
      const unsigned char* sW = wimg + (size_t)(c + 2) * PWCHUNK + t * 16;
      unsigned char* dW = smem + ((c + 2) % 3) * PWCHUNK + t * 16;
#pragma unroll
      for (int i = 0; i < 6; ++i) gl_lds16(sW + i * 8192, dW + i * 8192);
    }
    __builtin_amdgcn_sched_barrier(0);
    // (e) MFMA
    const unsigned char* WB = smem + (c % 3) * PWCHUNK;
    const unsigned char* AB = smem + PAOFF + (c % 3) * 4096;
    bf16x8 af0 = *(const bf16x8*)(AB + afh[0]);
    bf16x8 af1 = *(const bf16x8*)(AB + afh[1]);
    __builtin_amdgcn_s_setprio(1);
#pragma unroll
    for (int ns = 0; ns < 12; ++ns) {
      int n = wn * 192 + ns * 16 + ln;
      bf16x8 bfrag = *(const bf16x8*)(WB + n * 64 + ((g ^ ((n >> 1) & 3)) << 4));
      acc[0][ns] = __builtin_amdgcn_mfma_f32_16x16x32_bf16(af0, bfrag, acc[0][ns], 0, 0, 0);
      acc[1][ns] = __builtin_amdgcn_mfma_f32_16x16x32_bf16(af1, bfrag, acc[1][ns], 0, 0, 0);
    }
    __builtin_amdgcn_s_setprio(0);
    a1 = a2;
  }

#pragma unroll
  for (int ns = 0; ns < 12; ++ns) {
    int col = wn * 192 + ns * 16 + ln;
    float pbv = pb[col];
#pragma unroll
    for (int sm = 0; sm < 2; ++sm)
#pragma unroll
      for (int r = 0; r < 4; ++r)
        dst[(row0 + wm * 32 + sm * 16 + 4 * g + r) * DM + col] = acc[sm][ns][r] + pbv;
  }
}

// ---------------- attn fallback (round-2 verified): used if ws too small ------
__global__ __launch_bounds__(512, 2) void attn_kernel_fb(
    const float* __restrict__ x, const float* __restrict__ qkv_w,
    const float* __restrict__ qkv_b, const float* __restrict__ edge_bias,
    const float* __restrict__ mask, float* __restrict__ out)
{
  __shared__ __align__(16) unsigned char smem[98304];
  const int t = threadIdx.x;
  const int lane = t & 63;
  const int w = t >> 6;
  const int g = lane >> 4;
  const int ln = lane & 15;
  const int wm = w & 3;
  const int wn = w >> 2;

  const int orig = blockIdx.x;
  const int wg = (orig & 7) * 768 + (orig >> 3);
  const int h = wg % 12;
  const int bn = wg / 12;

  const float* xw = x + (size_t)bn * (WT * DM);

  f32x4 acc[2][6];
#pragma unroll
  for (int i = 0; i < 2; ++i)
#pragma unroll
    for (int j = 0; j < 6; ++j) acc[i][j] = (f32x4){0.f, 0.f, 0.f, 0.f};

  float4 wreg[6], xreg[8];
#pragma unroll
  for (int q = 0; q < 6; ++q) {
    int fid = q * 512 + t;
    int j = fid >> 4, c4 = fid & 15;
    int sec = j >> 6, d = j & 63;
    wreg[q] = *(const float4*)(qkv_w + (size_t)(sec * DM + h * 64 + d) * DM + c4 * 4);
  }

  for (int c = 0; c < 12; ++c) {
    const int kc = c * 64;
#pragma unroll
    for (int sm = 0; sm < 2; ++sm)
#pragma unroll
      for (int ks = 0; ks < 2; ++ks) {
        int row = wm * 32 + sm * 16 + ln;
        const float* p = xw + (size_t)row * DM + kc + ks * 32 + g * 8;
        xreg[(sm * 2 + ks) * 2 + 0] = *(const float4*)p;
        xreg[(sm * 2 + ks) * 2 + 1] = *(const float4*)(p + 4);
      }
    unsigned char* WH = smem + (c & 1) * 49152;
    unsigned char* WL = WH + 24576;
#pragma unroll
    for (int q = 0; q < 6; ++q) {
      int fid = q * 512 + t;
      int j = fid >> 4, c4 = fid & 15;
      int byte = j * 128 + ((((c4 >> 1) ^ (j & 7))) << 4) + ((c4 & 1) << 3);
      float4 v = wreg[q];
      unsigned short h0, h1, h2, h3, l0, l1, l2, l3;
      bf_split(v.x, h0, l0); bf_split(v.y, h1, l1);
      bf_split(v.z, h2, l2); bf_split(v.w, h3, l3);
      uint2 hv, lv;
      hv.x = (unsigned)h0 | ((unsigned)h1 << 16); hv.y = (unsigned)h2 | ((unsigned)h3 << 16);
      lv.x = (unsigned)l0 | ((unsigned)l1 << 16); lv.y = (unsigned)l2 | ((unsigned)l3 << 16);
      *(uint2*)(WH + byte) = hv;
      *(uint2*)(WL + byte) = lv;
    }
    if (c < 11) {
#pragma unroll
      for (int q = 0; q < 6; ++q) {
        int fid = q * 512 + t;
        int j = fid >> 4, c4 = fid & 15;
        int sec = j >> 6, d = j & 63;
        wreg[q] = *(const float4*)(qkv_w + (size_t)(sec * DM + h * 64 + d) * DM + kc + 64 + c4 * 4);
      }
    }
    __syncthreads();
#pragma unroll
    for (int ks = 0; ks < 2; ++ks) {
      bf16x8 ah[2], al[2];
#pragma unroll
      for (int sm = 0; sm < 2; ++sm)
        split8(xreg[(sm * 2 + ks) * 2 + 0], xreg[(sm * 2 + ks) * 2 + 1], ah[sm], al[sm]);
#pragma unroll
      for (int ns = 0; ns < 6; ++ns) {
        int j = wn * 96 + ns * 16 + ln;
        int sw = j * 128 + (((ks * 4 + g) ^ (j & 7)) << 4);
        bf16x8 bh = *(const bf16x8*)(WH + sw);
        bf16x8 bl = *(const bf16x8*)(WL + sw);
#pragma unroll
        for (int sm = 0; sm < 2; ++sm) {
          acc[sm][ns] = __builtin_amdgcn_mfma_f32_16x16x32_bf16(ah[sm], bh, acc[sm][ns], 0, 0, 0);
          acc[sm][ns] = __builtin_amdgcn_mfma_f32_16x16x32_bf16(ah[sm], bl, acc[sm][ns], 0, 0, 0);
          acc[sm][ns] = __builtin_amdgcn_mfma_f32_16x16x32_bf16(al[sm], bh, acc[sm][ns], 0, 0, 0);
        }
      }
    }
  }
  __syncthreads();

#pragma unroll
  for (int sm = 0; sm < 2; ++sm)
#pragma unroll
    for (int ns = 0; ns < 6; ++ns) {
      int cc = wn * 96 + ns * 16 + ln;
      int sec = cc >> 6, dd = cc & 63;
      float bias = qkv_b[sec * DM + h * 64 + dd];
#pragma unroll
      for (int r = 0; r < 4; ++r) {
        int m = wm * 32 + sm * 16 + 4 * g + r;
        float val = acc[sm][ns][r] + bias;
        if (cc < 64) {
          val *= 0.125f;
          unsigned short hi, lo; bf_split(val, hi, lo);
          int byte = m * 128 + ((((dd >> 3) ^ (m & 7))) << 4) + ((dd & 7) << 1);
          *(unsigned short*)(smem + QH_OFF + byte) = hi;
          *(unsigned short*)(smem + QL_OFF + byte) = lo;
        } else if (cc < 128) {
          unsigned short hi, lo; bf_split(val, hi, lo);
          int byte = m * 128 + ((((dd >> 3) ^ (m & 7))) << 4) + ((dd & 7) << 1);
          *(unsigned short*)(smem + KH_OFF + byte) = hi;
          *(unsigned short*)(smem + KL_OFF + byte) = lo;
        } else {
          *(unsigned short*)(smem + VT_OFF + dd * 272 + m * 2) = bf_rne(val);
        }
      }
    }
  __syncthreads();

  const int mB = w * 16;
  f32x4 s2[8];
#pragma unroll
  for (int ns = 0; ns < 8; ++ns) s2[ns] = (f32x4){0.f, 0.f, 0.f, 0.f};
#pragma unroll
  for (int ks = 0; ks < 2; ++ks) {
    int arow = mB + ln;
    int abyte = arow * 128 + (((ks * 4 + g) ^ (arow & 7)) << 4);
    bf16x8 qh = *(const bf16x8*)(smem + QH_OFF + abyte);
    bf16x8 ql = *(const bf16x8*)(smem + QL_OFF + abyte);
#pragma unroll
    for (int ns = 0; ns < 8; ++ns) {
      int brow = ns * 16 + ln;
      int bbyte = brow * 128 + (((ks * 4 + g) ^ (brow & 7)) << 4);
      bf16x8 kh = *(const bf16x8*)(smem + KH_OFF + bbyte);
      bf16x8 kl = *(const bf16x8*)(smem + KL_OFF + bbyte);
      s2[ns] = __builtin_amdgcn_mfma_f32_16x16x32_bf16(qh, kh, s2[ns], 0, 0, 0);
      s2[ns] = __builtin_amdgcn_mfma_f32_16x16x32_bf16(qh, kl, s2[ns], 0, 0, 0);
      s2[ns] = __builtin_amdgcn_mfma_f32_16x16x32_bf16(ql, kh, s2[ns], 0, 0, 0);
    }
  }
  __syncthreads();

  const float* mk = mask + (size_t)(bn & 127) * (WT * WT);
  const float* eb = edge_bias + (size_t)h * (WT * WT);
#pragma unroll
  for (int r = 0; r < 4; ++r) {
    int m = mB + 4 * g + r;
    float sv[8];
#pragma unroll
    for (int ns = 0; ns < 8; ++ns) sv[ns] = s2[ns][r];
    float m1 = sv[0];
#pragma unroll
    for (int ns = 1; ns < 8; ++ns) m1 = fmaxf(m1, sv[ns]);
#pragma unroll
    for (int off = 1; off < 16; off <<= 1) m1 = fmaxf(m1, __shfl_xor(m1, off, 64));
    float e[8], sum1 = 0.f;
#pragma unroll
    for (int ns = 0; ns < 8; ++ns) { e[ns] = __expf(sv[ns] - m1); sum1 += e[ns]; }
#pragma unroll
    for (int off = 1; off < 16; off <<= 1) sum1 += __shfl_xor(sum1, off, 64);
    float thr = 0.5f * sum1;
    float tv[8];
#pragma unroll
    for (int ns = 0; ns < 8; ++ns) {
      int col = ns * 16 + ln;
      float mkv = mk[m * WT + col];
      float ebv = eb[m * WT + col];
      float keep = (e[ns] > thr) ? 0.f : 1.f;
      float val = sv[ns] * keep * mkv * ebv;
      tv[ns] = (val == 0.f) ? -10000.f : val;
    }
    float m2 = tv[0];
#pragma unroll
    for (int ns = 1; ns < 8; ++ns) m2 = fmaxf(m2, tv[ns]);
#pragma unroll
    for (int off = 1; off < 16; off <<= 1) m2 = fmaxf(m2, __shfl_xor(m2, off, 64));
    float e2[8], sum2 = 0.f;
#pragma unroll
    for (int ns = 0; ns < 8; ++ns) { e2[ns] = __expf(tv[ns] - m2); sum2 += e2[ns]; }
#pragma unroll
    for (int off = 1; off < 16; off <<= 1) sum2 += __shfl_xor(sum2, off, 64);
    float inv = 1.f / sum2;
#pragma unroll
    for (int ns = 0; ns < 8; ++ns)
      *(unsigned short*)(smem + P_OFF + m * 272 + (ns * 16 + ln) * 2) = bf_rne(e2[ns] * inv);
  }
  __syncthreads();

  f32x4 o4[4];
#pragma unroll
  for (int ns = 0; ns < 4; ++ns) o4[ns] = (f32x4){0.f, 0.f, 0.f, 0.f};
#pragma unroll
  for (int ks = 0; ks < 4; ++ks) {
    bf16x8 pa = *(const bf16x8*)(smem + P_OFF + (mB + ln) * 272 + ks * 64 + g * 16);
#pragma unroll
    for (int ns = 0; ns < 4; ++ns) {
      bf16x8 vb = *(const bf16x8*)(smem + VT_OFF + (ns * 16 + ln) * 272 + ks * 64 + g * 16);
      o4[ns] = __builtin_amdgcn_mfma_f32_16x16x32_bf16(pa, vb, o4[ns], 0, 0, 0);
    }
  }
#pragma unroll
  for (int ns = 0; ns < 4; ++ns)
#pragma unroll
    for (int r = 0; r < 4; ++r)
      out[(size_t)bn * (WT * DM) + (size_t)(mB + 4 * g + r) * DM + h * 64 + ns * 16 + ln] = o4[ns][r];
}

// ---------------- proj fallback: round-2/3 verified 64-row version ------------
#define PA_OFF 0
#define PW_OFF 98304

__global__ __launch_bounds__(512, 2) void proj_kernel_fb(
    const float* src, const float* __restrict__ pw,
    const float* __restrict__ pb, float* dst)
{
  __shared__ __align__(16) unsigned char smem[147456];
  const int t = threadIdx.x;
  const int lane = t & 63;
  const int w = t >> 6;
  const int g = lane >> 4;
  const int ln = lane & 15;
  const int wm = w & 1;
  const int wn = w >> 1;

  const int orig = blockIdx.x;
  const int wg = (orig & 7) * 128 + (orig >> 3);
  const size_t row0 = (size_t)wg * 64;

#pragma unroll
  for (int q = 0; q < 24; ++q) {
    int fid = q * 512 + t;
    int row = fid / 192, c4 = fid % 192;
    float4 v = *(const float4*)(src + (row0 + row) * DM + c4 * 4);
    int slot = c4 >> 1;
    int byte = row * 1536 + (((slot & ~7) | ((slot & 7) ^ (row & 7))) << 4) + ((c4 & 1) << 3);
    uint2 hv;
    hv.x = (unsigned)bf_rne(v.x) | ((unsigned)bf_rne(v.y) << 16);
    hv.y = (unsigned)bf_rne(v.z) | ((unsigned)bf_rne(v.w) << 16);
    *(uint2*)(smem + PA_OFF + byte) = hv;
  }

  f32x4 accp[2][12];
#pragma unroll
  for (int i = 0; i < 2; ++i)
#pragma unroll
    for (int j = 0; j < 12; ++j) accp[i][j] = (f32x4){0.f, 0.f, 0.f, 0.f};

  for (int c = 0; c < 24; ++c) {
    const int kc = c * 32;
    __syncthreads();
#pragma unroll
    for (int q = 0; q < 12; ++q) {
      int fid = q * 512 + t;
      int n = fid >> 3, c4 = fid & 7;
      float4 v = *(const float4*)(pw + (size_t)n * DM + kc + c4 * 4);
      int slot = (n & 1) * 4 + (c4 >> 1);
      int byte = (n >> 1) * 128 + ((slot ^ ((n >> 1) & 7)) << 4) + ((c4 & 1) << 3);
      uint2 hv;
      hv.x = (unsigned)bf_rne(v.x) | ((unsigned)bf_rne(v.y) << 16);
      hv.y = (unsigned)bf_rne(v.z) | ((unsigned)bf_rne(v.w) << 16);
      *(uint2*)(smem + PW_OFF + byte) = hv;
    }
    __syncthreads();
    bf16x8 af[2];
#pragma unroll
    for (int sm = 0; sm < 2; ++sm) {
      int row = wm * 32 + sm * 16 + ln;
      int slot = (kc >> 3) + g;
      int byte = row * 1536 + (((slot & ~7) | ((slot & 7) ^ (row & 7))) << 4);
      af[sm] = *(const bf16x8*)(smem + PA_OFF + byte);
    }
#pragma unroll
    for (int j = 0; j < 12; ++j) {
      int n = (wn * 12 + j) * 16 + ln;
      int slot = (n & 1) * 4 + g;
      bf16x8 bf_ = *(const bf16x8*)(smem + PW_OFF + (n >> 1) * 128 + ((slot ^ ((n >> 1) & 7)) << 4));
#pragma unroll
      for (int sm = 0; sm < 2; ++sm)
        accp[sm][j] = __builtin_amdgcn_mfma_f32_16x16x32_bf16(af[sm], bf_, accp[sm][j], 0, 0, 0);
    }
  }

#pragma unroll
  for (int j = 0; j < 12; ++j) {
    int col = (wn * 12 + j) * 16 + ln;
    float pbv = pb[col];
#pragma unroll
    for (int sm = 0; sm < 2; ++sm)
#pragma unroll
      for (int r = 0; r < 4; ++r)
        dst[(row0 + wm * 32 + sm * 16 + 4 * g + r) * DM + col] = accp[sm][j][r] + pbv;
  }
}

extern "C" void kernel_launch(void* const* d_in, const int* in_sizes, int n_in,
                              void* d_out, int out_size, void* d_ws, size_t ws_size,
                              hipStream_t stream) {
  const float* x         = (const float*)d_in[0];
  const float* qkv_w     = (const float*)d_in[1];
  const float* qkv_b     = (const float*)d_in[2];
  const float* proj_w    = (const float*)d_in[3];
  const float* proj_b    = (const float*)d_in[4];
  const float* edge_bias = (const float*)d_in[5];
  const float* mask      = (const float*)d_in[6];
  float* out = (float*)d_out;

  const bool p1 = (d_ws != nullptr) && (ws_size >= WS_W1);
  const bool p2 = (d_ws != nullptr) && (ws_size >= WS_W1 + WS_W2);
  unsigned char* wsW = (unsigned char*)d_ws;
  unsigned char* wsP = wsW + WS_W1;

  if (p1) {
    split_w_kernel<<<1728, 256, 0, stream>>>(qkv_w, wsW);
  }
  if (p2) {
    split_pw_kernel<<<576, 256, 0, stream>>>(proj_w, wsP);
  }
  if (p1) {
    attn_kernel_pre<<<NW * NH, 512, 0, stream>>>(x, wsW, qkv_b, edge_bias, mask, out);
  } else {
    attn_kernel_fb<<<NW * NH, 512, 0, stream>>>(x, qkv_w, qkv_b, edge_bias, mask, out);
  }
  if (p2) {
    proj_kernel_pre<<<1024, 512, 0, stream>>>(out, wsP, proj_b, out);
  } else {
    proj_kernel_fb<<<1024, 512, 0, stream>>>(out, proj_w, proj_b, out);
  }
}